// Round 3
// baseline (1405.935 us; speedup 1.0000x reference)
//
#include <hip/hip_runtime.h>
#include <stdint.h>

typedef unsigned short ushort_t;
typedef float f32x4 __attribute__((ext_vector_type(4)));
typedef short bh8 __attribute__((ext_vector_type(8)));

#define NROWS 8192
#define DIN   4096
#define HENC  1024
#define DM    512
#define KC    64
#define HDEC  2048

__device__ __forceinline__ float bf2f(ushort_t u) {
  union { unsigned int i; float f; } v; v.i = ((unsigned int)u) << 16; return v.f;
}
__device__ __forceinline__ ushort_t f2bf(float f) {
  unsigned int x = __float_as_uint(f);
  unsigned int r = x + 0x7FFFu + ((x >> 16) & 1u);
  return (ushort_t)(r >> 16);
}
__device__ __forceinline__ void split_bf(float x, ushort_t& hi, ushort_t& lo) {
  ushort_t h = f2bf(x);
  hi = h;
  lo = f2bf(x - bf2f(h));
}

// ---------------- fp32 tiled GEMM (encoder path: accuracy-critical) -------------
// C[M,N] = A[M,K] @ B[K,N] + bias
// EPI: 0 = relu -> f32;  1 = f32 + bf16 hi/lo split;  2 = f32 plain
template<int BM, int BN, int EPI>
__launch_bounds__(256, 2)
__global__ void gemm_f32_k(const float* __restrict__ A, const float* __restrict__ B,
                           const float* __restrict__ bias, float* __restrict__ Cf,
                           ushort_t* __restrict__ Ch, ushort_t* __restrict__ Cl,
                           int M, int N, int K) {
  constexpr int TM = BM / 16, TN = BN / 16;
  __shared__ float As[16][BM + 4];  // stored transposed: As[k][m]
  __shared__ float Bs[16][BN + 4];
  const int t = threadIdx.x;
  const int tx = t & 15, ty = t >> 4;
  const int m0 = blockIdx.y * BM, n0 = blockIdx.x * BN;
  float acc[TM][TN];
#pragma unroll
  for (int i = 0; i < TM; ++i)
#pragma unroll
    for (int j = 0; j < TN; ++j) acc[i][j] = 0.f;

  const int ar = t >> 2, ac = (t & 3) * 4;
  const int bk = t >> 4;

  for (int k0 = 0; k0 < K; k0 += 16) {
#pragma unroll
    for (int ii = 0; ii < BM / 64; ++ii) {
      int rr = ar + ii * 64;
      float4 v = *(const float4*)(A + (size_t)(m0 + rr) * K + k0 + ac);
      As[ac + 0][rr] = v.x; As[ac + 1][rr] = v.y;
      As[ac + 2][rr] = v.z; As[ac + 3][rr] = v.w;
    }
#pragma unroll
    for (int jj = 0; jj < BN / 64; ++jj) {
      int nn = (t & 15) * 4 * (BN / 64) + jj * 4;
      float4 v = *(const float4*)(B + (size_t)(k0 + bk) * N + n0 + nn);
      *(float4*)&Bs[bk][nn] = v;
    }
    __syncthreads();
#pragma unroll
    for (int kk = 0; kk < 16; ++kk) {
      float a[TM], b[TN];
#pragma unroll
      for (int i = 0; i < TM; i += 4) {
        float4 v = *(const float4*)&As[kk][ty * TM + i];
        a[i] = v.x; a[i + 1] = v.y; a[i + 2] = v.z; a[i + 3] = v.w;
      }
#pragma unroll
      for (int j = 0; j < TN; j += 4) {
        float4 v = *(const float4*)&Bs[kk][tx * TN + j];
        b[j] = v.x; b[j + 1] = v.y; b[j + 2] = v.z; b[j + 3] = v.w;
      }
#pragma unroll
      for (int i = 0; i < TM; ++i)
#pragma unroll
        for (int j = 0; j < TN; ++j) acc[i][j] = fmaf(a[i], b[j], acc[i][j]);
    }
    __syncthreads();
  }
#pragma unroll
  for (int i = 0; i < TM; ++i) {
    int row = m0 + ty * TM + i;
#pragma unroll
    for (int j = 0; j < TN; ++j) {
      int col = n0 + tx * TN + j;
      float v = acc[i][j] + bias[col];
      if (EPI == 0) v = fmaxf(v, 0.f);
      Cf[(size_t)row * N + col] = v;
      if (EPI == 1) {
        ushort_t h, l; split_bf(v, h, l);
        Ch[(size_t)row * N + col] = h;
        Cl[(size_t)row * N + col] = l;
      }
    }
  }
}

// ---------------- bf16 MFMA GEMM, single pass: C = A[M,K] @ BT[N,K]^T ----------
// EPI 2: f32 out + bias + relu (pred)
__device__ __forceinline__ void async_cp16(const ushort_t* g, ushort_t* l) {
  __builtin_amdgcn_global_load_lds((const __attribute__((address_space(1))) unsigned int*)g,
                                   (__attribute__((address_space(3))) unsigned int*)l,
                                   16, 0, 0);
}

template<int EPI>
__launch_bounds__(256, 2)
__global__ void gemm_bf16_k(const ushort_t* __restrict__ A, const ushort_t* __restrict__ BT,
                            const float* __restrict__ bias, float* __restrict__ Cf,
                            int M, int N, int K) {
  __shared__ ushort_t lA[128 * 32];
  __shared__ ushort_t lB[128 * 32];
  const int t = threadIdx.x;
  const int w = t >> 6, lane = t & 63;
  const int wm = w >> 1, wn = w & 1;
  const int m0 = blockIdx.y * 128, n0 = blockIdx.x * 128;
  f32x4 acc[4][4] = {};
  const int lr = lane & 15, lk = (lane >> 4) * 8;
  const int sm = lane >> 2, sk = (lane & 3) * 8;

  for (int k0 = 0; k0 < K; k0 += 32) {
#pragma unroll
    for (int q = 0; q < 2; ++q) {
      const int ci = w * 2 + q;
      const int mr = ci * 16 + sm;
      async_cp16(A  + (size_t)(m0 + mr) * K + k0 + sk, lA + ci * 512);
      async_cp16(BT + (size_t)(n0 + mr) * K + k0 + sk, lB + ci * 512);
    }
    __syncthreads();
    bh8 av[4], bv[4];
#pragma unroll
    for (int mi = 0; mi < 4; ++mi)
      av[mi] = *(const bh8*)&lA[(wm * 64 + mi * 16 + lr) * 32 + lk];
#pragma unroll
    for (int ni = 0; ni < 4; ++ni)
      bv[ni] = *(const bh8*)&lB[(wn * 64 + ni * 16 + lr) * 32 + lk];
#pragma unroll
    for (int mi = 0; mi < 4; ++mi)
#pragma unroll
      for (int ni = 0; ni < 4; ++ni)
        acc[mi][ni] = __builtin_amdgcn_mfma_f32_16x16x32_bf16(av[mi], bv[ni], acc[mi][ni], 0, 0, 0);
    __syncthreads();
  }
  const int rb = (lane >> 4) * 4;
#pragma unroll
  for (int mi = 0; mi < 4; ++mi) {
#pragma unroll
    for (int ni = 0; ni < 4; ++ni) {
      int col = n0 + wn * 64 + ni * 16 + lr;
      float bval = bias[col];
#pragma unroll
      for (int r = 0; r < 4; ++r) {
        int row = m0 + wm * 64 + mi * 16 + rb + r;
        float v = acc[mi][ni][r] + bval;
        if (EPI == 2) v = fmaxf(v, 0.f);
        Cf[(size_t)row * N + col] = v;
      }
    }
  }
}

// ---------------- split-bf16 3-pass MFMA GEMM: fp32-quality ---------------------
// C = (Ah+Al)[M,K] @ (Bh+Bl)[N,K]^T, acc = Ah·Bh + Ah·Bl + Al·Bh
// EPI: 0 = f32 out, no bias (fw);  1 = bf16 out + bias + BN column stats (h1)
template<int EPI>
__launch_bounds__(256, 2)
__global__ void gemm_bf16x2_k(const ushort_t* __restrict__ Ah, const ushort_t* __restrict__ Al,
                              const ushort_t* __restrict__ Bh, const ushort_t* __restrict__ Bl,
                              const float* __restrict__ bias, float* __restrict__ Cf,
                              ushort_t* __restrict__ Cb, float* __restrict__ bnsum,
                              int M, int N, int K) {
  __shared__ ushort_t lAh[4096], lAl[4096], lBh[4096], lBl[4096];
  __shared__ float csum[128], csum2[128];
  const int t = threadIdx.x;
  const int w = t >> 6, lane = t & 63;
  const int wm = w >> 1, wn = w & 1;
  const int m0 = blockIdx.y * 128, n0 = blockIdx.x * 128;
  f32x4 acc[4][4] = {};
  const int lr = lane & 15, lk = (lane >> 4) * 8;
  const int sm = lane >> 2, sk = (lane & 3) * 8;

  for (int k0 = 0; k0 < K; k0 += 32) {
#pragma unroll
    for (int q = 0; q < 2; ++q) {
      const int ci = w * 2 + q;
      const int mr = ci * 16 + sm;
      async_cp16(Ah + (size_t)(m0 + mr) * K + k0 + sk, lAh + ci * 512);
      async_cp16(Al + (size_t)(m0 + mr) * K + k0 + sk, lAl + ci * 512);
      async_cp16(Bh + (size_t)(n0 + mr) * K + k0 + sk, lBh + ci * 512);
      async_cp16(Bl + (size_t)(n0 + mr) * K + k0 + sk, lBl + ci * 512);
    }
    __syncthreads();
    bh8 avh[4], avl[4], bvh[4], bvl[4];
#pragma unroll
    for (int mi = 0; mi < 4; ++mi) {
      avh[mi] = *(const bh8*)&lAh[(wm * 64 + mi * 16 + lr) * 32 + lk];
      avl[mi] = *(const bh8*)&lAl[(wm * 64 + mi * 16 + lr) * 32 + lk];
    }
#pragma unroll
    for (int ni = 0; ni < 4; ++ni) {
      bvh[ni] = *(const bh8*)&lBh[(wn * 64 + ni * 16 + lr) * 32 + lk];
      bvl[ni] = *(const bh8*)&lBl[(wn * 64 + ni * 16 + lr) * 32 + lk];
    }
#pragma unroll
    for (int mi = 0; mi < 4; ++mi)
#pragma unroll
      for (int ni = 0; ni < 4; ++ni) {
        acc[mi][ni] = __builtin_amdgcn_mfma_f32_16x16x32_bf16(avh[mi], bvh[ni], acc[mi][ni], 0, 0, 0);
        acc[mi][ni] = __builtin_amdgcn_mfma_f32_16x16x32_bf16(avh[mi], bvl[ni], acc[mi][ni], 0, 0, 0);
        acc[mi][ni] = __builtin_amdgcn_mfma_f32_16x16x32_bf16(avl[mi], bvh[ni], acc[mi][ni], 0, 0, 0);
      }
    __syncthreads();
  }
  if (EPI == 1) {
    if (t < 128) { csum[t] = 0.f; csum2[t] = 0.f; }
    __syncthreads();
  }
  const int rb = (lane >> 4) * 4;
#pragma unroll
  for (int mi = 0; mi < 4; ++mi) {
#pragma unroll
    for (int ni = 0; ni < 4; ++ni) {
      int lcol = wn * 64 + ni * 16 + lr;
      int col = n0 + lcol;
      float bval = (EPI == 1) ? bias[col] : 0.f;
      float s = 0.f, s2 = 0.f;
#pragma unroll
      for (int r = 0; r < 4; ++r) {
        int row = m0 + wm * 64 + mi * 16 + rb + r;
        float v = acc[mi][ni][r] + bval;
        if (EPI == 0) {
          Cf[(size_t)row * N + col] = v;
        } else {
          Cb[(size_t)row * N + col] = f2bf(v);
          s += v; s2 = fmaf(v, v, s2);
        }
      }
      if (EPI == 1) {
        atomicAdd(&csum[lcol], s);
        atomicAdd(&csum2[lcol], s2);
      }
    }
  }
  if (EPI == 1) {
    __syncthreads();
    if (t < 128) {
      atomicAdd(&bnsum[n0 + t], csum[t]);
      atomicAdd(&bnsum[N + n0 + t], csum2[t]);
    }
  }
}

// ---------------- transpose + cast: W f32 [K][N] -> WT bf16 [N][K] -------------
// SPLIT: also emit lo part
template<bool SPLIT>
__global__ void tcast_k(const float* __restrict__ W, ushort_t* __restrict__ WTh,
                        ushort_t* __restrict__ WTl, int K, int N) {
  __shared__ float tile[32][33];
  const int bx = blockIdx.x * 32, by = blockIdx.y * 32;
  const int tx = threadIdx.x & 31, ty8 = threadIdx.x >> 5;
  for (int i = ty8; i < 32; i += 8)
    tile[i][tx] = W[(size_t)(by + i) * N + bx + tx];
  __syncthreads();
  for (int i = ty8; i < 32; i += 8) {
    float v = tile[tx][i];
    if (SPLIT) {
      ushort_t h, l; split_bf(v, h, l);
      WTh[(size_t)(bx + i) * K + by + tx] = h;
      WTl[(size_t)(bx + i) * K + by + tx] = l;
    } else {
      WTh[(size_t)(bx + i) * K + by + tx] = f2bf(v);
    }
  }
}

// ---------------- gumbel softmax + hard assignment + l2-normalize --------------
__global__ void gumbel_k(const float* __restrict__ logits, const float* __restrict__ u1,
                         const float* __restrict__ u2, float* __restrict__ gout,
                         float* __restrict__ assign) {
  const int lane = threadIdx.x & 63;
  const int row = blockIdx.x * 4 + (threadIdx.x >> 6);
  const size_t off = (size_t)row * KC + lane;
  const float lg = logits[off];

  float gn = -logf(-logf(u1[off] + 1e-20f) + 1e-20f);
  float s = lg + gn;
  float m = s;
#pragma unroll
  for (int o = 32; o; o >>= 1) m = fmaxf(m, __shfl_xor(m, o, 64));
  float e = expf(s - m);
  float sum = e;
#pragma unroll
  for (int o = 32; o; o >>= 1) sum += __shfl_xor(sum, o, 64);
  float y = e / sum;
  float l2 = y * y;
#pragma unroll
  for (int o = 32; o; o >>= 1) l2 += __shfl_xor(l2, o, 64);
  gout[off] = y * rsqrtf(fmaxf(l2, 1e-12f));

  float gn2 = -logf(-logf(u2[off] + 1e-20f) + 1e-20f);
  float s2 = lg + gn2;
  float m2 = s2; int bi = lane;
#pragma unroll
  for (int o = 32; o; o >>= 1) {
    float om = __shfl_xor(m2, o, 64);
    int   oi = __shfl_xor(bi, o, 64);
    if (om > m2 || (om == m2 && oi < bi)) { m2 = om; bi = oi; }
  }
  assign[off] = (lane == bi) ? 1.0f : 0.0f;
}

// ---------------- t = g^T @ fw  ([64,8192] @ [8192,512] -> [64,512]) -----------
__global__ void gtfw_k(const float* __restrict__ g, const float* __restrict__ fw,
                       float* __restrict__ tmat) {
  __shared__ float lf[64 * 64];
  __shared__ float lg[64 * 64];
  const int t = threadIdx.x;
  const int k = t & 63, ng = t >> 6;
  const int nb = blockIdx.x, rc = blockIdx.y;
  float acc[16];
#pragma unroll
  for (int j = 0; j < 16; ++j) acc[j] = 0.f;
  for (int rt = 0; rt < 8; ++rt) {
    const int r0 = rc * 512 + rt * 64;
#pragma unroll
    for (int j = 0; j < 4; ++j) {
      int e = t * 16 + j * 4;
      int rr = e >> 6, cc = e & 63;
      *(float4*)&lf[e] = *(const float4*)&fw[(size_t)(r0 + rr) * DM + nb * 64 + cc];
      *(float4*)&lg[e] = *(const float4*)&g[(size_t)(r0 + rr) * KC + cc];
    }
    __syncthreads();
    for (int r = 0; r < 64; ++r) {
      float gv = lg[r * 64 + k];
      const float* lrow = &lf[r * 64 + ng * 16];
#pragma unroll
      for (int j = 0; j < 16; j += 4) {
        float4 b = *(const float4*)&lrow[j];
        acc[j]     += gv * b.x; acc[j + 1] += gv * b.y;
        acc[j + 2] += gv * b.z; acc[j + 3] += gv * b.w;
      }
    }
    __syncthreads();
  }
#pragma unroll
  for (int j = 0; j < 16; ++j)
    atomicAdd(&tmat[(size_t)k * DM + nb * 64 + ng * 16 + j], acc[j]);
}

// ---------------- gcn = relu(g @ t + bg) -> bf16 hi/lo -------------------------
__global__ void gcn_k(const float* __restrict__ g, const float* __restrict__ tmat,
                      const float* __restrict__ bg, ushort_t* __restrict__ gh,
                      ushort_t* __restrict__ gl) {
  __shared__ float gs[64 * 68];
  __shared__ float ts[64 * 68];
  const int t = threadIdx.x;
  const int tx = t & 15, ty = t >> 4;
  const int m0 = blockIdx.y * 64, n0 = blockIdx.x * 64;
#pragma unroll
  for (int j = 0; j < 4; ++j) {
    int e = t * 16 + j * 4;
    int rr = e >> 6, cc = e & 63;
    *(float4*)&gs[rr * 68 + cc] = *(const float4*)&g[(size_t)(m0 + rr) * KC + cc];
    *(float4*)&ts[rr * 68 + cc] = *(const float4*)&tmat[(size_t)rr * DM + n0 + cc];
  }
  __syncthreads();
  float acc[4][4];
#pragma unroll
  for (int i = 0; i < 4; ++i)
#pragma unroll
    for (int j = 0; j < 4; ++j) acc[i][j] = 0.f;
  for (int kk = 0; kk < 64; ++kk) {
    float a[4];
#pragma unroll
    for (int i = 0; i < 4; ++i) a[i] = gs[(ty * 4 + i) * 68 + kk];
    float4 b = *(const float4*)&ts[kk * 68 + tx * 4];
#pragma unroll
    for (int i = 0; i < 4; ++i) {
      acc[i][0] = fmaf(a[i], b.x, acc[i][0]);
      acc[i][1] = fmaf(a[i], b.y, acc[i][1]);
      acc[i][2] = fmaf(a[i], b.z, acc[i][2]);
      acc[i][3] = fmaf(a[i], b.w, acc[i][3]);
    }
  }
#pragma unroll
  for (int i = 0; i < 4; ++i) {
    int row = m0 + ty * 4 + i;
#pragma unroll
    for (int j = 0; j < 4; ++j) {
      int col = n0 + tx * 4 + j;
      float v = fmaxf(acc[i][j] + bg[col], 0.f);
      ushort_t h, l; split_bf(v, h, l);
      gh[(size_t)row * DM + col] = h;
      gl[(size_t)row * DM + col] = l;
    }
  }
}

// ---------------- batch-norm finalize + in-place apply -------------------------
__global__ void bn_final_k(const float* __restrict__ sums, const float* __restrict__ gamma,
                           const float* __restrict__ beta, float* __restrict__ scale,
                           float* __restrict__ shift) {
  int c = blockIdx.x * 256 + threadIdx.x;
  float mu = sums[c] * (1.f / NROWS);
  float var = fmaxf(sums[HDEC + c] * (1.f / NROWS) - mu * mu, 0.f);
  float rstd = rsqrtf(var + 1e-3f);
  float sc = gamma[c] * rstd;
  scale[c] = sc;
  shift[c] = beta[c] - mu * sc;
}

__global__ void bn_apply_k(ushort_t* __restrict__ h1, const float* __restrict__ scale,
                           const float* __restrict__ shift) {
  size_t i8 = ((size_t)blockIdx.x * 256 + threadIdx.x) * 8;
  int col = (int)(i8 & (HDEC - 1));
  bh8 v = *(const bh8*)&h1[i8];
  bh8 o;
#pragma unroll
  for (int j = 0; j < 8; ++j) {
    float f = bf2f((ushort_t)v[j]);
    f = fmaxf(fmaf(f, scale[col + j], shift[col + j]), 0.f);
    o[j] = (short)f2bf(f);
  }
  *(bh8*)&h1[i8] = o;
}

// -------------------------------------------------------------------------------
extern "C" void kernel_launch(void* const* d_in, const int* in_sizes, int n_in,
                              void* d_out, int out_size, void* d_ws, size_t ws_size,
                              hipStream_t stream) {
  const float* x    = (const float*)d_in[0];
  const float* u1   = (const float*)d_in[1];
  const float* u2   = (const float*)d_in[2];
  const float* We1  = (const float*)d_in[3];
  const float* be1  = (const float*)d_in[4];
  const float* We2  = (const float*)d_in[5];
  const float* be2  = (const float*)d_in[6];
  const float* Wfc  = (const float*)d_in[7];
  const float* bfc  = (const float*)d_in[8];
  const float* Wg   = (const float*)d_in[9];
  const float* bg   = (const float*)d_in[10];
  const float* Wd1  = (const float*)d_in[11];
  const float* bd1  = (const float*)d_in[12];
  const float* gamma = (const float*)d_in[13];
  const float* beta  = (const float*)d_in[14];
  const float* Wd2  = (const float*)d_in[15];
  const float* bd2  = (const float*)d_in[16];
  (void)in_sizes; (void)n_in; (void)out_size; (void)ws_size;

  // outputs fp32: pred | assignment | feat
  float* out = (float*)d_out;
  float* pred_o   = out;
  float* assign_o = out + (size_t)NROWS * DIN;
  float* feat_o   = assign_o + (size_t)NROWS * KC;

  char* ws = (char*)d_ws;
  const size_t MB = 1024 * 1024;
  // R0 [0,32MB): ench f32 (enc phase); then gcn hi/lo + Wd1T hi/lo + tmat + bn
  float*    ench    = (float*)(ws + 0);
  ushort_t* gcn_hi  = (ushort_t*)(ws + 0);
  ushort_t* gcn_lo  = (ushort_t*)(ws + 8 * MB);
  ushort_t* Wd1T_hi = (ushort_t*)(ws + 16 * MB);
  ushort_t* Wd1T_lo = (ushort_t*)(ws + 18 * MB);
  float*    tmat    = (float*)(ws + 20 * MB);
  float*    bnsum   = (float*)(ws + 21 * MB);                 // 2*2048 f32
  float*    bnscale = (float*)(ws + 21 * MB + 16 * 1024);
  float*    bnshift = (float*)(ws + 21 * MB + 24 * 1024);
  // R1 [32,65.5MB): feat hi/lo + fw (pre-decoder); then h1 bf16 (33.5MB)
  ushort_t* feat_hi = (ushort_t*)(ws + 32 * MB);
  ushort_t* feat_lo = (ushort_t*)(ws + 40 * MB);
  float*    fw      = (float*)(ws + 48 * MB);
  ushort_t* h1      = (ushort_t*)(ws + 32 * MB);
  // R2 [66,87MB): WgT hi/lo, logits, gmat, Wd2T
  ushort_t* WgT_hi  = (ushort_t*)(ws + 66 * MB);
  ushort_t* WgT_lo  = (ushort_t*)(ws + 66 * MB + 512 * 1024);
  float*    logits  = (float*)(ws + 67 * MB);
  float*    gmat    = (float*)(ws + 69 * MB);
  ushort_t* Wd2T    = (ushort_t*)(ws + 71 * MB);

  // upfront weight casts in independent regions
  tcast_k<true><<<dim3(DM / 32, DM / 32), 256, 0, stream>>>(Wg, WgT_hi, WgT_lo, DM, DM);
  tcast_k<false><<<dim3(DIN / 32, HDEC / 32), 256, 0, stream>>>(Wd2, Wd2T, nullptr, HDEC, DIN);

  // encoder (fp32 — argmax-accuracy-critical)
  gemm_f32_k<128, 128, 0><<<dim3(HENC / 128, NROWS / 128), 256, 0, stream>>>(
      x, We1, be1, ench, nullptr, nullptr, NROWS, HENC, DIN);
  gemm_f32_k<64, 128, 1><<<dim3(DM / 128, NROWS / 64), 256, 0, stream>>>(
      ench, We2, be2, feat_o, feat_hi, feat_lo, NROWS, DM, HENC);
  // ench now dead -> R0 reusable
  tcast_k<true><<<dim3(HDEC / 32, DM / 32), 256, 0, stream>>>(Wd1, Wd1T_hi, Wd1T_lo, DM, HDEC);
  gemm_f32_k<64, 64, 2><<<dim3(KC / 64, NROWS / 64), 256, 0, stream>>>(
      feat_o, Wfc, bfc, logits, nullptr, nullptr, NROWS, KC, DM);

  gumbel_k<<<dim3(NROWS / 4), 256, 0, stream>>>(logits, u1, u2, gmat, assign_o);

  // fw = feat @ Wg (split-bf16 3-pass, fp32-quality)
  gemm_bf16x2_k<0><<<dim3(DM / 128, NROWS / 128), 256, 0, stream>>>(
      feat_hi, feat_lo, WgT_hi, WgT_lo, nullptr, fw, nullptr, nullptr, NROWS, DM, DM);

  // gcn = relu(g (g^T fw) + bg) — adjacency factored out; all f32
  hipMemsetAsync(tmat, 0, (size_t)KC * DM * 4, stream);
  gtfw_k<<<dim3(DM / 64, NROWS / 512), 256, 0, stream>>>(gmat, fw, tmat);
  gcn_k<<<dim3(DM / 64, NROWS / 64), 256, 0, stream>>>(gmat, tmat, bg, gcn_hi, gcn_lo);

  // h1 = gcn @ Wd1 + bd1 (split-bf16 3-pass) + fused BN stats from f32 acc
  hipMemsetAsync(bnsum, 0, 2 * HDEC * 4, stream);
  gemm_bf16x2_k<1><<<dim3(HDEC / 128, NROWS / 128), 256, 0, stream>>>(
      gcn_hi, gcn_lo, Wd1T_hi, Wd1T_lo, bd1, nullptr, h1, bnsum, NROWS, HDEC, DM);

  // batch norm finalize + in-place apply (h1 -> hbn)
  bn_final_k<<<dim3(HDEC / 256), 256, 0, stream>>>(bnsum, gamma, beta, bnscale, bnshift);
  bn_apply_k<<<dim3((NROWS * HDEC / 8) / 256), 256, 0, stream>>>(h1, bnscale, bnshift);

  // pred = relu(hbn @ Wd2 + bd2) -> f32 d_out (single-pass bf16)
  gemm_bf16_k<2><<<dim3(DIN / 128, NROWS / 128), 256, 0, stream>>>(
      h1, Wd2T, bd2, pred_o, NROWS, DIN, HDEC);
}

// Round 5
// 910.086 us; speedup vs baseline: 1.5448x; 1.5448x over previous
//
#include <hip/hip_runtime.h>
#include <stdint.h>

typedef unsigned short ushort_t;
typedef float f32x4 __attribute__((ext_vector_type(4)));
typedef short bh8 __attribute__((ext_vector_type(8)));

#define NROWS 8192
#define DIN   4096
#define HENC  1024
#define DM    512
#define KC    64
#define HDEC  2048

__device__ __forceinline__ float bf2f(ushort_t u) {
  union { unsigned int i; float f; } v; v.i = ((unsigned int)u) << 16; return v.f;
}
__device__ __forceinline__ ushort_t f2bf(float f) {
  unsigned int x = __float_as_uint(f);
  unsigned int r = x + 0x7FFFu + ((x >> 16) & 1u);
  return (ushort_t)(r >> 16);
}
__device__ __forceinline__ void split_bf(float x, ushort_t& hi, ushort_t& lo) {
  ushort_t h = f2bf(x);
  hi = h;
  lo = f2bf(x - bf2f(h));
}

// ---------------- fp32 tiled GEMM (small encoder tail + fallback) ---------------
// C[M,N] = A[M,K] @ B[K,N] + bias
// EPI: 0 = relu -> f32;  1 = f32 + bf16 hi/lo split;  2 = f32 plain
template<int BM, int BN, int EPI>
__launch_bounds__(256, 2)
__global__ void gemm_f32_k(const float* __restrict__ A, const float* __restrict__ B,
                           const float* __restrict__ bias, float* __restrict__ Cf,
                           ushort_t* __restrict__ Ch, ushort_t* __restrict__ Cl,
                           int M, int N, int K) {
  constexpr int TM = BM / 16, TN = BN / 16;
  __shared__ float As[16][BM + 4];  // stored transposed: As[k][m]
  __shared__ float Bs[16][BN + 4];
  const int t = threadIdx.x;
  const int tx = t & 15, ty = t >> 4;
  const int m0 = blockIdx.y * BM, n0 = blockIdx.x * BN;
  float acc[TM][TN];
#pragma unroll
  for (int i = 0; i < TM; ++i)
#pragma unroll
    for (int j = 0; j < TN; ++j) acc[i][j] = 0.f;

  const int ar = t >> 2, ac = (t & 3) * 4;
  const int bk = t >> 4;

  for (int k0 = 0; k0 < K; k0 += 16) {
#pragma unroll
    for (int ii = 0; ii < BM / 64; ++ii) {
      int rr = ar + ii * 64;
      float4 v = *(const float4*)(A + (size_t)(m0 + rr) * K + k0 + ac);
      As[ac + 0][rr] = v.x; As[ac + 1][rr] = v.y;
      As[ac + 2][rr] = v.z; As[ac + 3][rr] = v.w;
    }
#pragma unroll
    for (int jj = 0; jj < BN / 64; ++jj) {
      int nn = (t & 15) * 4 * (BN / 64) + jj * 4;
      float4 v = *(const float4*)(B + (size_t)(k0 + bk) * N + n0 + nn);
      *(float4*)&Bs[bk][nn] = v;
    }
    __syncthreads();
#pragma unroll
    for (int kk = 0; kk < 16; ++kk) {
      float a[TM], b[TN];
#pragma unroll
      for (int i = 0; i < TM; i += 4) {
        float4 v = *(const float4*)&As[kk][ty * TM + i];
        a[i] = v.x; a[i + 1] = v.y; a[i + 2] = v.z; a[i + 3] = v.w;
      }
#pragma unroll
      for (int j = 0; j < TN; j += 4) {
        float4 v = *(const float4*)&Bs[kk][tx * TN + j];
        b[j] = v.x; b[j + 1] = v.y; b[j + 2] = v.z; b[j + 3] = v.w;
      }
#pragma unroll
      for (int i = 0; i < TM; ++i)
#pragma unroll
        for (int j = 0; j < TN; ++j) acc[i][j] = fmaf(a[i], b[j], acc[i][j]);
    }
    __syncthreads();
  }
#pragma unroll
  for (int i = 0; i < TM; ++i) {
    int row = m0 + ty * TM + i;
#pragma unroll
    for (int j = 0; j < TN; ++j) {
      int col = n0 + tx * TN + j;
      float v = acc[i][j] + bias[col];
      if (EPI == 0) v = fmaxf(v, 0.f);
      Cf[(size_t)row * N + col] = v;
      if (EPI == 1) {
        ushort_t h, l; split_bf(v, h, l);
        Ch[(size_t)row * N + col] = h;
        Cl[(size_t)row * N + col] = l;
      }
    }
  }
}

// ---------------- bf16 MFMA GEMM, single pass: C = A[M,K] @ BT[N,K]^T ----------
// EPI 2: f32 out + bias + relu (pred)
__device__ __forceinline__ void async_cp16(const ushort_t* g, ushort_t* l) {
  __builtin_amdgcn_global_load_lds((const __attribute__((address_space(1))) unsigned int*)g,
                                   (__attribute__((address_space(3))) unsigned int*)l,
                                   16, 0, 0);
}

template<int EPI>
__launch_bounds__(256, 2)
__global__ void gemm_bf16_k(const ushort_t* __restrict__ A, const ushort_t* __restrict__ BT,
                            const float* __restrict__ bias, float* __restrict__ Cf,
                            int M, int N, int K) {
  __shared__ ushort_t lA[128 * 32];
  __shared__ ushort_t lB[128 * 32];
  const int t = threadIdx.x;
  const int w = t >> 6, lane = t & 63;
  const int wm = w >> 1, wn = w & 1;
  const int m0 = blockIdx.y * 128, n0 = blockIdx.x * 128;
  f32x4 acc[4][4] = {};
  const int lr = lane & 15, lk = (lane >> 4) * 8;
  const int sm = lane >> 2, sk = (lane & 3) * 8;

  for (int k0 = 0; k0 < K; k0 += 32) {
#pragma unroll
    for (int q = 0; q < 2; ++q) {
      const int ci = w * 2 + q;
      const int mr = ci * 16 + sm;
      async_cp16(A  + (size_t)(m0 + mr) * K + k0 + sk, lA + ci * 512);
      async_cp16(BT + (size_t)(n0 + mr) * K + k0 + sk, lB + ci * 512);
    }
    __syncthreads();
    bh8 av[4], bv[4];
#pragma unroll
    for (int mi = 0; mi < 4; ++mi)
      av[mi] = *(const bh8*)&lA[(wm * 64 + mi * 16 + lr) * 32 + lk];
#pragma unroll
    for (int ni = 0; ni < 4; ++ni)
      bv[ni] = *(const bh8*)&lB[(wn * 64 + ni * 16 + lr) * 32 + lk];
#pragma unroll
    for (int mi = 0; mi < 4; ++mi)
#pragma unroll
      for (int ni = 0; ni < 4; ++ni)
        acc[mi][ni] = __builtin_amdgcn_mfma_f32_16x16x32_bf16(av[mi], bv[ni], acc[mi][ni], 0, 0, 0);
    __syncthreads();
  }
  const int rb = (lane >> 4) * 4;
#pragma unroll
  for (int mi = 0; mi < 4; ++mi) {
#pragma unroll
    for (int ni = 0; ni < 4; ++ni) {
      int col = n0 + wn * 64 + ni * 16 + lr;
      float bval = bias[col];
#pragma unroll
      for (int r = 0; r < 4; ++r) {
        int row = m0 + wm * 64 + mi * 16 + rb + r;
        float v = acc[mi][ni][r] + bval;
        if (EPI == 2) v = fmaxf(v, 0.f);
        Cf[(size_t)row * N + col] = v;
      }
    }
  }
}

// ---------------- split-bf16 multi-pass MFMA GEMM: fp32-quality -----------------
// C = (Ah+Al)[M,K] @ (Bh+Bl)[N,K]^T
// P4=false: acc = AhBh + AhBl + AlBh (3-pass); P4=true: + AlBl (4-pass)
// EPI: 0 = f32 out, no bias (fw)
//      1 = bf16 out + bias + BN column stats (h1)
//      2 = f32 out + bias + relu (ench)
template<int EPI, bool P4>
__launch_bounds__(256, 2)
__global__ void gemm_bf16x2_k(const ushort_t* __restrict__ Ah, const ushort_t* __restrict__ Al,
                              const ushort_t* __restrict__ Bh, const ushort_t* __restrict__ Bl,
                              const float* __restrict__ bias, float* __restrict__ Cf,
                              ushort_t* __restrict__ Cb, float* __restrict__ bnsum,
                              int M, int N, int K) {
  __shared__ ushort_t lAh[4096], lAl[4096], lBh[4096], lBl[4096];
  __shared__ float csum[128], csum2[128];
  const int t = threadIdx.x;
  const int w = t >> 6, lane = t & 63;
  const int wm = w >> 1, wn = w & 1;
  const int m0 = blockIdx.y * 128, n0 = blockIdx.x * 128;
  f32x4 acc[4][4] = {};
  const int lr = lane & 15, lk = (lane >> 4) * 8;
  const int sm = lane >> 2, sk = (lane & 3) * 8;

  for (int k0 = 0; k0 < K; k0 += 32) {
#pragma unroll
    for (int q = 0; q < 2; ++q) {
      const int ci = w * 2 + q;
      const int mr = ci * 16 + sm;
      async_cp16(Ah + (size_t)(m0 + mr) * K + k0 + sk, lAh + ci * 512);
      async_cp16(Al + (size_t)(m0 + mr) * K + k0 + sk, lAl + ci * 512);
      async_cp16(Bh + (size_t)(n0 + mr) * K + k0 + sk, lBh + ci * 512);
      async_cp16(Bl + (size_t)(n0 + mr) * K + k0 + sk, lBl + ci * 512);
    }
    __syncthreads();
    bh8 avh[4], avl[4], bvh[4], bvl[4];
#pragma unroll
    for (int mi = 0; mi < 4; ++mi) {
      avh[mi] = *(const bh8*)&lAh[(wm * 64 + mi * 16 + lr) * 32 + lk];
      avl[mi] = *(const bh8*)&lAl[(wm * 64 + mi * 16 + lr) * 32 + lk];
    }
#pragma unroll
    for (int ni = 0; ni < 4; ++ni) {
      bvh[ni] = *(const bh8*)&lBh[(wn * 64 + ni * 16 + lr) * 32 + lk];
      bvl[ni] = *(const bh8*)&lBl[(wn * 64 + ni * 16 + lr) * 32 + lk];
    }
#pragma unroll
    for (int mi = 0; mi < 4; ++mi)
#pragma unroll
      for (int ni = 0; ni < 4; ++ni) {
        acc[mi][ni] = __builtin_amdgcn_mfma_f32_16x16x32_bf16(avh[mi], bvh[ni], acc[mi][ni], 0, 0, 0);
        acc[mi][ni] = __builtin_amdgcn_mfma_f32_16x16x32_bf16(avh[mi], bvl[ni], acc[mi][ni], 0, 0, 0);
        acc[mi][ni] = __builtin_amdgcn_mfma_f32_16x16x32_bf16(avl[mi], bvh[ni], acc[mi][ni], 0, 0, 0);
        if (P4)
          acc[mi][ni] = __builtin_amdgcn_mfma_f32_16x16x32_bf16(avl[mi], bvl[ni], acc[mi][ni], 0, 0, 0);
      }
    __syncthreads();
  }
  if (EPI == 1) {
    if (t < 128) { csum[t] = 0.f; csum2[t] = 0.f; }
    __syncthreads();
  }
  const int rb = (lane >> 4) * 4;
#pragma unroll
  for (int mi = 0; mi < 4; ++mi) {
#pragma unroll
    for (int ni = 0; ni < 4; ++ni) {
      int lcol = wn * 64 + ni * 16 + lr;
      int col = n0 + lcol;
      float bval = (EPI == 0) ? 0.f : bias[col];
      float s = 0.f, s2 = 0.f;
#pragma unroll
      for (int r = 0; r < 4; ++r) {
        int row = m0 + wm * 64 + mi * 16 + rb + r;
        float v = acc[mi][ni][r] + bval;
        if (EPI == 0) {
          Cf[(size_t)row * N + col] = v;
        } else if (EPI == 2) {
          Cf[(size_t)row * N + col] = fmaxf(v, 0.f);
        } else {
          Cb[(size_t)row * N + col] = f2bf(v);
          s += v; s2 = fmaf(v, v, s2);
        }
      }
      if (EPI == 1) {
        atomicAdd(&csum[lcol], s);
        atomicAdd(&csum2[lcol], s2);
      }
    }
  }
  if (EPI == 1) {
    __syncthreads();
    if (t < 128) {
      atomicAdd(&bnsum[n0 + t], csum[t]);
      atomicAdd(&bnsum[N + n0 + t], csum2[t]);
    }
  }
}

// ---------------- transpose + cast: W f32 [K][N] -> WT bf16 [N][K] -------------
template<bool SPLIT>
__global__ void tcast_k(const float* __restrict__ W, ushort_t* __restrict__ WTh,
                        ushort_t* __restrict__ WTl, int K, int N) {
  __shared__ float tile[32][33];
  const int bx = blockIdx.x * 32, by = blockIdx.y * 32;
  const int tx = threadIdx.x & 31, ty8 = threadIdx.x >> 5;
  for (int i = ty8; i < 32; i += 8)
    tile[i][tx] = W[(size_t)(by + i) * N + bx + tx];
  __syncthreads();
  for (int i = ty8; i < 32; i += 8) {
    float v = tile[tx][i];
    if (SPLIT) {
      ushort_t h, l; split_bf(v, h, l);
      WTh[(size_t)(bx + i) * K + by + tx] = h;
      WTl[(size_t)(bx + i) * K + by + tx] = l;
    } else {
      WTh[(size_t)(bx + i) * K + by + tx] = f2bf(v);
    }
  }
}

// ---------------- elementwise f32 -> bf16 hi/lo split (row-major kept) ---------
__global__ void fsplit_k(const float* __restrict__ X, ushort_t* __restrict__ H,
                         ushort_t* __restrict__ L) {
  size_t i8 = ((size_t)blockIdx.x * 256 + threadIdx.x) * 8;
  float4 a = *(const float4*)&X[i8];
  float4 b = *(const float4*)&X[i8 + 4];
  bh8 h, l;
  float vv[8] = {a.x, a.y, a.z, a.w, b.x, b.y, b.z, b.w};
#pragma unroll
  for (int j = 0; j < 8; ++j) {
    ushort_t hh, ll; split_bf(vv[j], hh, ll);
    h[j] = (short)hh; l[j] = (short)ll;
  }
  *(bh8*)&H[i8] = h;
  *(bh8*)&L[i8] = l;
}

// ---------------- gumbel softmax + hard assignment + l2-normalize --------------
__global__ void gumbel_k(const float* __restrict__ logits, const float* __restrict__ u1,
                         const float* __restrict__ u2, float* __restrict__ gout,
                         float* __restrict__ assign) {
  const int lane = threadIdx.x & 63;
  const int row = blockIdx.x * 4 + (threadIdx.x >> 6);
  const size_t off = (size_t)row * KC + lane;
  const float lg = logits[off];

  float gn = -logf(-logf(u1[off] + 1e-20f) + 1e-20f);
  float s = lg + gn;
  float m = s;
#pragma unroll
  for (int o = 32; o; o >>= 1) m = fmaxf(m, __shfl_xor(m, o, 64));
  float e = expf(s - m);
  float sum = e;
#pragma unroll
  for (int o = 32; o; o >>= 1) sum += __shfl_xor(sum, o, 64);
  float y = e / sum;
  float l2 = y * y;
#pragma unroll
  for (int o = 32; o; o >>= 1) l2 += __shfl_xor(l2, o, 64);
  gout[off] = y * rsqrtf(fmaxf(l2, 1e-12f));

  float gn2 = -logf(-logf(u2[off] + 1e-20f) + 1e-20f);
  float s2 = lg + gn2;
  float m2 = s2; int bi = lane;
#pragma unroll
  for (int o = 32; o; o >>= 1) {
    float om = __shfl_xor(m2, o, 64);
    int   oi = __shfl_xor(bi, o, 64);
    if (om > m2 || (om == m2 && oi < bi)) { m2 = om; bi = oi; }
  }
  assign[off] = (lane == bi) ? 1.0f : 0.0f;
}

// ---------------- t = g^T @ fw  ([64,8192] @ [8192,512] -> [64,512]) -----------
__global__ void gtfw_k(const float* __restrict__ g, const float* __restrict__ fw,
                       float* __restrict__ tmat) {
  __shared__ float lf[64 * 64];
  __shared__ float lg[64 * 64];
  const int t = threadIdx.x;
  const int k = t & 63, ng = t >> 6;
  const int nb = blockIdx.x, rc = blockIdx.y;
  float acc[16];
#pragma unroll
  for (int j = 0; j < 16; ++j) acc[j] = 0.f;
  for (int rt = 0; rt < 8; ++rt) {
    const int r0 = rc * 512 + rt * 64;
#pragma unroll
    for (int j = 0; j < 4; ++j) {
      int e = t * 16 + j * 4;
      int rr = e >> 6, cc = e & 63;
      *(float4*)&lf[e] = *(const float4*)&fw[(size_t)(r0 + rr) * DM + nb * 64 + cc];
      *(float4*)&lg[e] = *(const float4*)&g[(size_t)(r0 + rr) * KC + cc];
    }
    __syncthreads();
    for (int r = 0; r < 64; ++r) {
      float gv = lg[r * 64 + k];
      const float* lrow = &lf[r * 64 + ng * 16];
#pragma unroll
      for (int j = 0; j < 16; j += 4) {
        float4 b = *(const float4*)&lrow[j];
        acc[j]     += gv * b.x; acc[j + 1] += gv * b.y;
        acc[j + 2] += gv * b.z; acc[j + 3] += gv * b.w;
      }
    }
    __syncthreads();
  }
#pragma unroll
  for (int j = 0; j < 16; ++j)
    atomicAdd(&tmat[(size_t)k * DM + nb * 64 + ng * 16 + j], acc[j]);
}

// ---------------- gcn = relu(g @ t + bg) -> bf16 hi/lo -------------------------
__global__ void gcn_k(const float* __restrict__ g, const float* __restrict__ tmat,
                      const float* __restrict__ bg, ushort_t* __restrict__ gh,
                      ushort_t* __restrict__ gl) {
  __shared__ float gs[64 * 68];
  __shared__ float ts[64 * 68];
  const int t = threadIdx.x;
  const int tx = t & 15, ty = t >> 4;
  const int m0 = blockIdx.y * 64, n0 = blockIdx.x * 64;
#pragma unroll
  for (int j = 0; j < 4; ++j) {
    int e = t * 16 + j * 4;
    int rr = e >> 6, cc = e & 63;
    *(float4*)&gs[rr * 68 + cc] = *(const float4*)&g[(size_t)(m0 + rr) * KC + cc];
    *(float4*)&ts[rr * 68 + cc] = *(const float4*)&tmat[(size_t)rr * DM + n0 + cc];
  }
  __syncthreads();
  float acc[4][4];
#pragma unroll
  for (int i = 0; i < 4; ++i)
#pragma unroll
    for (int j = 0; j < 4; ++j) acc[i][j] = 0.f;
  for (int kk = 0; kk < 64; ++kk) {
    float a[4];
#pragma unroll
    for (int i = 0; i < 4; ++i) a[i] = gs[(ty * 4 + i) * 68 + kk];
    float4 b = *(const float4*)&ts[kk * 68 + tx * 4];
#pragma unroll
    for (int i = 0; i < 4; ++i) {
      acc[i][0] = fmaf(a[i], b.x, acc[i][0]);
      acc[i][1] = fmaf(a[i], b.y, acc[i][1]);
      acc[i][2] = fmaf(a[i], b.z, acc[i][2]);
      acc[i][3] = fmaf(a[i], b.w, acc[i][3]);
    }
  }
#pragma unroll
  for (int i = 0; i < 4; ++i) {
    int row = m0 + ty * 4 + i;
#pragma unroll
    for (int j = 0; j < 4; ++j) {
      int col = n0 + tx * 4 + j;
      float v = fmaxf(acc[i][j] + bg[col], 0.f);
      ushort_t h, l; split_bf(v, h, l);
      gh[(size_t)row * DM + col] = h;
      gl[(size_t)row * DM + col] = l;
    }
  }
}

// ---------------- batch-norm finalize + in-place apply -------------------------
__global__ void bn_final_k(const float* __restrict__ sums, const float* __restrict__ gamma,
                           const float* __restrict__ beta, float* __restrict__ scale,
                           float* __restrict__ shift) {
  int c = blockIdx.x * 256 + threadIdx.x;
  float mu = sums[c] * (1.f / NROWS);
  float var = fmaxf(sums[HDEC + c] * (1.f / NROWS) - mu * mu, 0.f);
  float rstd = rsqrtf(var + 1e-3f);
  float sc = gamma[c] * rstd;
  scale[c] = sc;
  shift[c] = beta[c] - mu * sc;
}

__global__ void bn_apply_k(ushort_t* __restrict__ h1, const float* __restrict__ scale,
                           const float* __restrict__ shift) {
  size_t i8 = ((size_t)blockIdx.x * 256 + threadIdx.x) * 8;
  int col = (int)(i8 & (HDEC - 1));
  bh8 v = *(const bh8*)&h1[i8];
  bh8 o;
#pragma unroll
  for (int j = 0; j < 8; ++j) {
    float f = bf2f((ushort_t)v[j]);
    f = fmaxf(fmaf(f, scale[col + j], shift[col + j]), 0.f);
    o[j] = (short)f2bf(f);
  }
  *(bh8*)&h1[i8] = o;
}

// -------------------------------------------------------------------------------
extern "C" void kernel_launch(void* const* d_in, const int* in_sizes, int n_in,
                              void* d_out, int out_size, void* d_ws, size_t ws_size,
                              hipStream_t stream) {
  const float* x    = (const float*)d_in[0];
  const float* u1   = (const float*)d_in[1];
  const float* u2   = (const float*)d_in[2];
  const float* We1  = (const float*)d_in[3];
  const float* be1  = (const float*)d_in[4];
  const float* We2  = (const float*)d_in[5];
  const float* be2  = (const float*)d_in[6];
  const float* Wfc  = (const float*)d_in[7];
  const float* bfc  = (const float*)d_in[8];
  const float* Wg   = (const float*)d_in[9];
  const float* bg   = (const float*)d_in[10];
  const float* Wd1  = (const float*)d_in[11];
  const float* bd1  = (const float*)d_in[12];
  const float* gamma = (const float*)d_in[13];
  const float* beta  = (const float*)d_in[14];
  const float* Wd2  = (const float*)d_in[15];
  const float* bd2  = (const float*)d_in[16];
  (void)in_sizes; (void)n_in; (void)out_size;

  // outputs fp32: pred | assignment | feat
  float* out = (float*)d_out;
  float* pred_o   = out;
  float* assign_o = out + (size_t)NROWS * DIN;
  float* feat_o   = assign_o + (size_t)NROWS * KC;

  char* ws = (char*)d_ws;
  const size_t MB = 1024 * 1024;
  // R0 [0,32MB): ench f32 (enc phase); then gcn hi/lo + Wd1T hi/lo + tmat + bn
  float*    ench    = (float*)(ws + 0);
  ushort_t* gcn_hi  = (ushort_t*)(ws + 0);
  ushort_t* gcn_lo  = (ushort_t*)(ws + 8 * MB);
  ushort_t* Wd1T_hi = (ushort_t*)(ws + 16 * MB);
  ushort_t* Wd1T_lo = (ushort_t*)(ws + 18 * MB);
  float*    tmat    = (float*)(ws + 20 * MB);
  float*    bnsum   = (float*)(ws + 21 * MB);                 // 2*2048 f32
  float*    bnscale = (float*)(ws + 21 * MB + 16 * 1024);
  float*    bnshift = (float*)(ws + 21 * MB + 24 * 1024);
  // R1 [32,65.5MB): x_hi (enc1 phase) -> feat hi/lo + fw (pre-decoder) -> h1 bf16
  ushort_t* feat_hi = (ushort_t*)(ws + 32 * MB);
  ushort_t* feat_lo = (ushort_t*)(ws + 40 * MB);
  float*    fw      = (float*)(ws + 48 * MB);
  ushort_t* h1      = (ushort_t*)(ws + 32 * MB);
  // R2 [66,87MB): WgT, logits, gmat, Wd2T — NOTE: overlaps x_hi span, so these
  // are written only AFTER enc1 has consumed x_hi/x_lo.
  ushort_t* WgT_hi  = (ushort_t*)(ws + 66 * MB);
  ushort_t* WgT_lo  = (ushort_t*)(ws + 66 * MB + 512 * 1024);
  float*    logits  = (float*)(ws + 67 * MB);
  float*    gmat    = (float*)(ws + 69 * MB);
  ushort_t* Wd2T    = (ushort_t*)(ws + 71 * MB);
  // enc1 split scratch (dead after enc1): x_hi [32,96), x_lo [96,160), We1T [160,176)
  ushort_t* x_hi    = (ushort_t*)(ws + 32 * MB);
  ushort_t* x_lo    = (ushort_t*)(ws + 96 * MB);
  ushort_t* We1T_hi = (ushort_t*)(ws + 160 * MB);
  ushort_t* We1T_lo = (ushort_t*)(ws + 168 * MB);
  const bool use_split_enc1 = (ws_size >= 176 * MB);

  // ---- enc1: ench = relu(x @ We1 + be1) ----
  if (use_split_enc1) {
    tcast_k<true><<<dim3(HENC / 32, DIN / 32), 256, 0, stream>>>(We1, We1T_hi, We1T_lo, DIN, HENC);
    fsplit_k<<<dim3((NROWS * DIN / 8) / 256), 256, 0, stream>>>(x, x_hi, x_lo);
    gemm_bf16x2_k<2, true><<<dim3(HENC / 128, NROWS / 128), 256, 0, stream>>>(
        x_hi, x_lo, We1T_hi, We1T_lo, be1, ench, nullptr, nullptr, NROWS, HENC, DIN);
  } else {
    gemm_f32_k<128, 128, 0><<<dim3(HENC / 128, NROWS / 128), 256, 0, stream>>>(
        x, We1, be1, ench, nullptr, nullptr, NROWS, HENC, DIN);
  }

  // x_hi/x_lo now dead -> safe to fill R2 (overlaps x_hi span)
  tcast_k<true><<<dim3(DM / 32, DM / 32), 256, 0, stream>>>(Wg, WgT_hi, WgT_lo, DM, DM);
  tcast_k<false><<<dim3(DIN / 32, HDEC / 32), 256, 0, stream>>>(Wd2, Wd2T, nullptr, HDEC, DIN);

  // ---- enc2/enc3 (fp32 — argmax-accuracy-critical tail) ----
  gemm_f32_k<64, 128, 1><<<dim3(DM / 128, NROWS / 64), 256, 0, stream>>>(
      ench, We2, be2, feat_o, feat_hi, feat_lo, NROWS, DM, HENC);
  // ench now dead -> R0 reusable
  tcast_k<true><<<dim3(HDEC / 32, DM / 32), 256, 0, stream>>>(Wd1, Wd1T_hi, Wd1T_lo, DM, HDEC);
  gemm_f32_k<64, 64, 2><<<dim3(KC / 64, NROWS / 64), 256, 0, stream>>>(
      feat_o, Wfc, bfc, logits, nullptr, nullptr, NROWS, KC, DM);

  gumbel_k<<<dim3(NROWS / 4), 256, 0, stream>>>(logits, u1, u2, gmat, assign_o);

  // fw = feat @ Wg (split-bf16 3-pass, fp32-quality)
  gemm_bf16x2_k<0, false><<<dim3(DM / 128, NROWS / 128), 256, 0, stream>>>(
      feat_hi, feat_lo, WgT_hi, WgT_lo, nullptr, fw, nullptr, nullptr, NROWS, DM, DM);

  // gcn = relu(g (g^T fw) + bg) — adjacency factored out; all f32
  hipMemsetAsync(tmat, 0, (size_t)KC * DM * 4, stream);
  gtfw_k<<<dim3(DM / 64, NROWS / 512), 256, 0, stream>>>(gmat, fw, tmat);
  gcn_k<<<dim3(DM / 64, NROWS / 64), 256, 0, stream>>>(gmat, tmat, bg, gcn_hi, gcn_lo);

  // h1 = gcn @ Wd1 + bd1 (split-bf16 3-pass) + fused BN stats from f32 acc
  hipMemsetAsync(bnsum, 0, 2 * HDEC * 4, stream);
  gemm_bf16x2_k<1, false><<<dim3(HDEC / 128, NROWS / 128), 256, 0, stream>>>(
      gcn_hi, gcn_lo, Wd1T_hi, Wd1T_lo, bd1, nullptr, h1, bnsum, NROWS, HDEC, DM);

  // batch norm finalize + in-place apply (h1 -> hbn)
  bn_final_k<<<dim3(HDEC / 256), 256, 0, stream>>>(bnsum, gamma, beta, bnscale, bnshift);
  bn_apply_k<<<dim3((NROWS * HDEC / 8) / 256), 256, 0, stream>>>(h1, bnscale, bnshift);

  // pred = relu(hbn @ Wd2 + bd2) -> f32 d_out (single-pass bf16)
  gemm_bf16_k<2><<<dim3(DIN / 128, NROWS / 128), 256, 0, stream>>>(
      h1, Wd2T, bd2, pred_o, NROWS, DIN, HDEC);
}

// Round 6
// 850.748 us; speedup vs baseline: 1.6526x; 1.0697x over previous
//
#include <hip/hip_runtime.h>
#include <stdint.h>

typedef unsigned short ushort_t;
typedef float f32x4 __attribute__((ext_vector_type(4)));
typedef short bh8 __attribute__((ext_vector_type(8)));

#define NROWS 8192
#define DIN   4096
#define HENC  1024
#define DM    512
#define KC    64
#define HDEC  2048

__device__ __forceinline__ float bf2f(ushort_t u) {
  union { unsigned int i; float f; } v; v.i = ((unsigned int)u) << 16; return v.f;
}
__device__ __forceinline__ ushort_t f2bf(float f) {
  unsigned int x = __float_as_uint(f);
  unsigned int r = x + 0x7FFFu + ((x >> 16) & 1u);
  return (ushort_t)(r >> 16);
}
__device__ __forceinline__ void split_bf(float x, ushort_t& hi, ushort_t& lo) {
  ushort_t h = f2bf(x);
  hi = h;
  lo = f2bf(x - bf2f(h));
}

// ---------------- fp32 tiled GEMM (encoder tail + fallback path) ----------------
// C[M,N] = A[M,K] @ B[K,N] + bias
// EPI: 0 = relu -> f32;  1 = f32 + bf16 hi/lo split;  2 = f32 plain
template<int BM, int BN, int EPI>
__launch_bounds__(256, 2)
__global__ void gemm_f32_k(const float* __restrict__ A, const float* __restrict__ B,
                           const float* __restrict__ bias, float* __restrict__ Cf,
                           ushort_t* __restrict__ Ch, ushort_t* __restrict__ Cl,
                           int M, int N, int K) {
  constexpr int TM = BM / 16, TN = BN / 16;
  __shared__ float As[16][BM + 4];  // stored transposed: As[k][m]
  __shared__ float Bs[16][BN + 4];
  const int t = threadIdx.x;
  const int tx = t & 15, ty = t >> 4;
  const int m0 = blockIdx.y * BM, n0 = blockIdx.x * BN;
  float acc[TM][TN];
#pragma unroll
  for (int i = 0; i < TM; ++i)
#pragma unroll
    for (int j = 0; j < TN; ++j) acc[i][j] = 0.f;

  const int ar = t >> 2, ac = (t & 3) * 4;
  const int bk = t >> 4;

  for (int k0 = 0; k0 < K; k0 += 16) {
#pragma unroll
    for (int ii = 0; ii < BM / 64; ++ii) {
      int rr = ar + ii * 64;
      float4 v = *(const float4*)(A + (size_t)(m0 + rr) * K + k0 + ac);
      As[ac + 0][rr] = v.x; As[ac + 1][rr] = v.y;
      As[ac + 2][rr] = v.z; As[ac + 3][rr] = v.w;
    }
#pragma unroll
    for (int jj = 0; jj < BN / 64; ++jj) {
      int nn = (t & 15) * 4 * (BN / 64) + jj * 4;
      float4 v = *(const float4*)(B + (size_t)(k0 + bk) * N + n0 + nn);
      *(float4*)&Bs[bk][nn] = v;
    }
    __syncthreads();
#pragma unroll
    for (int kk = 0; kk < 16; ++kk) {
      float a[TM], b[TN];
#pragma unroll
      for (int i = 0; i < TM; i += 4) {
        float4 v = *(const float4*)&As[kk][ty * TM + i];
        a[i] = v.x; a[i + 1] = v.y; a[i + 2] = v.z; a[i + 3] = v.w;
      }
#pragma unroll
      for (int j = 0; j < TN; j += 4) {
        float4 v = *(const float4*)&Bs[kk][tx * TN + j];
        b[j] = v.x; b[j + 1] = v.y; b[j + 2] = v.z; b[j + 3] = v.w;
      }
#pragma unroll
      for (int i = 0; i < TM; ++i)
#pragma unroll
        for (int j = 0; j < TN; ++j) acc[i][j] = fmaf(a[i], b[j], acc[i][j]);
    }
    __syncthreads();
  }
#pragma unroll
  for (int i = 0; i < TM; ++i) {
    int row = m0 + ty * TM + i;
#pragma unroll
    for (int j = 0; j < TN; ++j) {
      int col = n0 + tx * TN + j;
      float v = acc[i][j] + bias[col];
      if (EPI == 0) v = fmaxf(v, 0.f);
      Cf[(size_t)row * N + col] = v;
      if (EPI == 1) {
        ushort_t h, l; split_bf(v, h, l);
        Ch[(size_t)row * N + col] = h;
        Cl[(size_t)row * N + col] = l;
      }
    }
  }
}

// ---------------- bf16 MFMA GEMM, single pass: C = A[M,K] @ BT[N,K]^T ----------
// EPI 2: f32 out + bias + relu (pred)
__device__ __forceinline__ void async_cp16(const ushort_t* g, ushort_t* l) {
  __builtin_amdgcn_global_load_lds((const __attribute__((address_space(1))) unsigned int*)g,
                                   (__attribute__((address_space(3))) unsigned int*)l,
                                   16, 0, 0);
}

template<int EPI>
__launch_bounds__(256, 2)
__global__ void gemm_bf16_k(const ushort_t* __restrict__ A, const ushort_t* __restrict__ BT,
                            const float* __restrict__ bias, float* __restrict__ Cf,
                            int M, int N, int K) {
  __shared__ ushort_t lA[128 * 32];
  __shared__ ushort_t lB[128 * 32];
  const int t = threadIdx.x;
  const int w = t >> 6, lane = t & 63;
  const int wm = w >> 1, wn = w & 1;
  const int m0 = blockIdx.y * 128, n0 = blockIdx.x * 128;
  f32x4 acc[4][4] = {};
  const int lr = lane & 15, lk = (lane >> 4) * 8;
  const int sm = lane >> 2, sk = (lane & 3) * 8;

  for (int k0 = 0; k0 < K; k0 += 32) {
#pragma unroll
    for (int q = 0; q < 2; ++q) {
      const int ci = w * 2 + q;
      const int mr = ci * 16 + sm;
      async_cp16(A  + (size_t)(m0 + mr) * K + k0 + sk, lA + ci * 512);
      async_cp16(BT + (size_t)(n0 + mr) * K + k0 + sk, lB + ci * 512);
    }
    __syncthreads();
    bh8 av[4], bv[4];
#pragma unroll
    for (int mi = 0; mi < 4; ++mi)
      av[mi] = *(const bh8*)&lA[(wm * 64 + mi * 16 + lr) * 32 + lk];
#pragma unroll
    for (int ni = 0; ni < 4; ++ni)
      bv[ni] = *(const bh8*)&lB[(wn * 64 + ni * 16 + lr) * 32 + lk];
#pragma unroll
    for (int mi = 0; mi < 4; ++mi)
#pragma unroll
      for (int ni = 0; ni < 4; ++ni)
        acc[mi][ni] = __builtin_amdgcn_mfma_f32_16x16x32_bf16(av[mi], bv[ni], acc[mi][ni], 0, 0, 0);
    __syncthreads();
  }
  const int rb = (lane >> 4) * 4;
#pragma unroll
  for (int mi = 0; mi < 4; ++mi) {
#pragma unroll
    for (int ni = 0; ni < 4; ++ni) {
      int col = n0 + wn * 64 + ni * 16 + lr;
      float bval = bias[col];
#pragma unroll
      for (int r = 0; r < 4; ++r) {
        int row = m0 + wm * 64 + mi * 16 + rb + r;
        float v = acc[mi][ni][r] + bval;
        if (EPI == 2) v = fmaxf(v, 0.f);
        Cf[(size_t)row * N + col] = v;
      }
    }
  }
}

// ---------------- split-bf16 multi-pass MFMA GEMM: fp32-quality -----------------
// C = (Ah+Al)[M,K] @ (Bh+Bl)[N,K]^T
// P4=false: acc = AhBh + AhBl + AlBh (3-pass); P4=true: + AlBl (4-pass)
// EPI: 0 = f32 out, no bias (fw)
//      1 = bf16 out (Cb) + bias + BN column stats (h1)
//      2 = bias + relu -> split hi/lo out (Cb=hi, Cl=lo)          (ench)
//      3 = bias -> f32 out (Cf) + split hi/lo out (Cb=hi, Cl=lo)  (feat)
template<int EPI, bool P4>
__launch_bounds__(256, 2)
__global__ void gemm_bf16x2_k(const ushort_t* __restrict__ Ah, const ushort_t* __restrict__ Al,
                              const ushort_t* __restrict__ Bh, const ushort_t* __restrict__ Bl,
                              const float* __restrict__ bias, float* __restrict__ Cf,
                              ushort_t* __restrict__ Cb, ushort_t* __restrict__ Cl,
                              float* __restrict__ bnsum, int M, int N, int K) {
  __shared__ ushort_t lAh[4096], lAl[4096], lBh[4096], lBl[4096];
  __shared__ float csum[128], csum2[128];
  const int t = threadIdx.x;
  const int w = t >> 6, lane = t & 63;
  const int wm = w >> 1, wn = w & 1;
  const int m0 = blockIdx.y * 128, n0 = blockIdx.x * 128;
  f32x4 acc[4][4] = {};
  const int lr = lane & 15, lk = (lane >> 4) * 8;
  const int sm = lane >> 2, sk = (lane & 3) * 8;

  for (int k0 = 0; k0 < K; k0 += 32) {
#pragma unroll
    for (int q = 0; q < 2; ++q) {
      const int ci = w * 2 + q;
      const int mr = ci * 16 + sm;
      async_cp16(Ah + (size_t)(m0 + mr) * K + k0 + sk, lAh + ci * 512);
      async_cp16(Al + (size_t)(m0 + mr) * K + k0 + sk, lAl + ci * 512);
      async_cp16(Bh + (size_t)(n0 + mr) * K + k0 + sk, lBh + ci * 512);
      async_cp16(Bl + (size_t)(n0 + mr) * K + k0 + sk, lBl + ci * 512);
    }
    __syncthreads();
    bh8 avh[4], avl[4], bvh[4], bvl[4];
#pragma unroll
    for (int mi = 0; mi < 4; ++mi) {
      avh[mi] = *(const bh8*)&lAh[(wm * 64 + mi * 16 + lr) * 32 + lk];
      avl[mi] = *(const bh8*)&lAl[(wm * 64 + mi * 16 + lr) * 32 + lk];
    }
#pragma unroll
    for (int ni = 0; ni < 4; ++ni) {
      bvh[ni] = *(const bh8*)&lBh[(wn * 64 + ni * 16 + lr) * 32 + lk];
      bvl[ni] = *(const bh8*)&lBl[(wn * 64 + ni * 16 + lr) * 32 + lk];
    }
#pragma unroll
    for (int mi = 0; mi < 4; ++mi)
#pragma unroll
      for (int ni = 0; ni < 4; ++ni) {
        acc[mi][ni] = __builtin_amdgcn_mfma_f32_16x16x32_bf16(avh[mi], bvh[ni], acc[mi][ni], 0, 0, 0);
        acc[mi][ni] = __builtin_amdgcn_mfma_f32_16x16x32_bf16(avh[mi], bvl[ni], acc[mi][ni], 0, 0, 0);
        acc[mi][ni] = __builtin_amdgcn_mfma_f32_16x16x32_bf16(avl[mi], bvh[ni], acc[mi][ni], 0, 0, 0);
        if (P4)
          acc[mi][ni] = __builtin_amdgcn_mfma_f32_16x16x32_bf16(avl[mi], bvl[ni], acc[mi][ni], 0, 0, 0);
      }
    __syncthreads();
  }
  if (EPI == 1) {
    if (t < 128) { csum[t] = 0.f; csum2[t] = 0.f; }
    __syncthreads();
  }
  const int rb = (lane >> 4) * 4;
#pragma unroll
  for (int mi = 0; mi < 4; ++mi) {
#pragma unroll
    for (int ni = 0; ni < 4; ++ni) {
      int lcol = wn * 64 + ni * 16 + lr;
      int col = n0 + lcol;
      float bval = (EPI == 0) ? 0.f : bias[col];
      float s = 0.f, s2 = 0.f;
#pragma unroll
      for (int r = 0; r < 4; ++r) {
        int row = m0 + wm * 64 + mi * 16 + rb + r;
        float v = acc[mi][ni][r] + bval;
        if (EPI == 0) {
          Cf[(size_t)row * N + col] = v;
        } else if (EPI == 1) {
          Cb[(size_t)row * N + col] = f2bf(v);
          s += v; s2 = fmaf(v, v, s2);
        } else if (EPI == 2) {
          v = fmaxf(v, 0.f);
          ushort_t h, l; split_bf(v, h, l);
          Cb[(size_t)row * N + col] = h;
          Cl[(size_t)row * N + col] = l;
        } else {  // EPI == 3
          Cf[(size_t)row * N + col] = v;
          ushort_t h, l; split_bf(v, h, l);
          Cb[(size_t)row * N + col] = h;
          Cl[(size_t)row * N + col] = l;
        }
      }
      if (EPI == 1) {
        atomicAdd(&csum[lcol], s);
        atomicAdd(&csum2[lcol], s2);
      }
    }
  }
  if (EPI == 1) {
    __syncthreads();
    if (t < 128) {
      atomicAdd(&bnsum[n0 + t], csum[t]);
      atomicAdd(&bnsum[N + n0 + t], csum2[t]);
    }
  }
}

// ---------------- transpose + cast: W f32 [K][N] -> WT bf16 [N][K] -------------
template<bool SPLIT>
__global__ void tcast_k(const float* __restrict__ W, ushort_t* __restrict__ WTh,
                        ushort_t* __restrict__ WTl, int K, int N) {
  __shared__ float tile[32][33];
  const int bx = blockIdx.x * 32, by = blockIdx.y * 32;
  const int tx = threadIdx.x & 31, ty8 = threadIdx.x >> 5;
  for (int i = ty8; i < 32; i += 8)
    tile[i][tx] = W[(size_t)(by + i) * N + bx + tx];
  __syncthreads();
  for (int i = ty8; i < 32; i += 8) {
    float v = tile[tx][i];
    if (SPLIT) {
      ushort_t h, l; split_bf(v, h, l);
      WTh[(size_t)(bx + i) * K + by + tx] = h;
      WTl[(size_t)(bx + i) * K + by + tx] = l;
    } else {
      WTh[(size_t)(bx + i) * K + by + tx] = f2bf(v);
    }
  }
}

// ---------------- elementwise f32 -> bf16 hi/lo split (row-major kept) ---------
__global__ void fsplit_k(const float* __restrict__ X, ushort_t* __restrict__ H,
                         ushort_t* __restrict__ L) {
  size_t i8 = ((size_t)blockIdx.x * 256 + threadIdx.x) * 8;
  float4 a = *(const float4*)&X[i8];
  float4 b = *(const float4*)&X[i8 + 4];
  bh8 h, l;
  float vv[8] = {a.x, a.y, a.z, a.w, b.x, b.y, b.z, b.w};
#pragma unroll
  for (int j = 0; j < 8; ++j) {
    ushort_t hh, ll; split_bf(vv[j], hh, ll);
    h[j] = (short)hh; l[j] = (short)ll;
  }
  *(bh8*)&H[i8] = h;
  *(bh8*)&L[i8] = l;
}

// ---------------- gumbel softmax + hard assignment + l2-normalize --------------
__global__ void gumbel_k(const float* __restrict__ logits, const float* __restrict__ u1,
                         const float* __restrict__ u2, float* __restrict__ gout,
                         float* __restrict__ assign) {
  const int lane = threadIdx.x & 63;
  const int row = blockIdx.x * 4 + (threadIdx.x >> 6);
  const size_t off = (size_t)row * KC + lane;
  const float lg = logits[off];

  float gn = -logf(-logf(u1[off] + 1e-20f) + 1e-20f);
  float s = lg + gn;
  float m = s;
#pragma unroll
  for (int o = 32; o; o >>= 1) m = fmaxf(m, __shfl_xor(m, o, 64));
  float e = expf(s - m);
  float sum = e;
#pragma unroll
  for (int o = 32; o; o >>= 1) sum += __shfl_xor(sum, o, 64);
  float y = e / sum;
  float l2 = y * y;
#pragma unroll
  for (int o = 32; o; o >>= 1) l2 += __shfl_xor(l2, o, 64);
  gout[off] = y * rsqrtf(fmaxf(l2, 1e-12f));

  float gn2 = -logf(-logf(u2[off] + 1e-20f) + 1e-20f);
  float s2 = lg + gn2;
  float m2 = s2; int bi = lane;
#pragma unroll
  for (int o = 32; o; o >>= 1) {
    float om = __shfl_xor(m2, o, 64);
    int   oi = __shfl_xor(bi, o, 64);
    if (om > m2 || (om == m2 && oi < bi)) { m2 = om; bi = oi; }
  }
  assign[off] = (lane == bi) ? 1.0f : 0.0f;
}

// ---------------- t = g^T @ fw  ([64,8192] @ [8192,512] -> [64,512]) -----------
__global__ void gtfw_k(const float* __restrict__ g, const float* __restrict__ fw,
                       float* __restrict__ tmat) {
  __shared__ float lf[64 * 64];
  __shared__ float lg[64 * 64];
  const int t = threadIdx.x;
  const int k = t & 63, ng = t >> 6;
  const int nb = blockIdx.x, rc = blockIdx.y;
  float acc[16];
#pragma unroll
  for (int j = 0; j < 16; ++j) acc[j] = 0.f;
  for (int rt = 0; rt < 8; ++rt) {
    const int r0 = rc * 512 + rt * 64;
#pragma unroll
    for (int j = 0; j < 4; ++j) {
      int e = t * 16 + j * 4;
      int rr = e >> 6, cc = e & 63;
      *(float4*)&lf[e] = *(const float4*)&fw[(size_t)(r0 + rr) * DM + nb * 64 + cc];
      *(float4*)&lg[e] = *(const float4*)&g[(size_t)(r0 + rr) * KC + cc];
    }
    __syncthreads();
    for (int r = 0; r < 64; ++r) {
      float gv = lg[r * 64 + k];
      const float* lrow = &lf[r * 64 + ng * 16];
#pragma unroll
      for (int j = 0; j < 16; j += 4) {
        float4 b = *(const float4*)&lrow[j];
        acc[j]     += gv * b.x; acc[j + 1] += gv * b.y;
        acc[j + 2] += gv * b.z; acc[j + 3] += gv * b.w;
      }
    }
    __syncthreads();
  }
#pragma unroll
  for (int j = 0; j < 16; ++j)
    atomicAdd(&tmat[(size_t)k * DM + nb * 64 + ng * 16 + j], acc[j]);
}

// ---------------- gcn = relu(g @ t + bg) -> bf16 hi/lo -------------------------
__global__ void gcn_k(const float* __restrict__ g, const float* __restrict__ tmat,
                      const float* __restrict__ bg, ushort_t* __restrict__ gh,
                      ushort_t* __restrict__ gl) {
  __shared__ float gs[64 * 68];
  __shared__ float ts[64 * 68];
  const int t = threadIdx.x;
  const int tx = t & 15, ty = t >> 4;
  const int m0 = blockIdx.y * 64, n0 = blockIdx.x * 64;
#pragma unroll
  for (int j = 0; j < 4; ++j) {
    int e = t * 16 + j * 4;
    int rr = e >> 6, cc = e & 63;
    *(float4*)&gs[rr * 68 + cc] = *(const float4*)&g[(size_t)(m0 + rr) * KC + cc];
    *(float4*)&ts[rr * 68 + cc] = *(const float4*)&tmat[(size_t)rr * DM + n0 + cc];
  }
  __syncthreads();
  float acc[4][4];
#pragma unroll
  for (int i = 0; i < 4; ++i)
#pragma unroll
    for (int j = 0; j < 4; ++j) acc[i][j] = 0.f;
  for (int kk = 0; kk < 64; ++kk) {
    float a[4];
#pragma unroll
    for (int i = 0; i < 4; ++i) a[i] = gs[(ty * 4 + i) * 68 + kk];
    float4 b = *(const float4*)&ts[kk * 68 + tx * 4];
#pragma unroll
    for (int i = 0; i < 4; ++i) {
      acc[i][0] = fmaf(a[i], b.x, acc[i][0]);
      acc[i][1] = fmaf(a[i], b.y, acc[i][1]);
      acc[i][2] = fmaf(a[i], b.z, acc[i][2]);
      acc[i][3] = fmaf(a[i], b.w, acc[i][3]);
    }
  }
#pragma unroll
  for (int i = 0; i < 4; ++i) {
    int row = m0 + ty * 4 + i;
#pragma unroll
    for (int j = 0; j < 4; ++j) {
      int col = n0 + tx * 4 + j;
      float v = fmaxf(acc[i][j] + bg[col], 0.f);
      ushort_t h, l; split_bf(v, h, l);
      gh[(size_t)row * DM + col] = h;
      gl[(size_t)row * DM + col] = l;
    }
  }
}

// ---------------- batch-norm finalize + in-place apply -------------------------
__global__ void bn_final_k(const float* __restrict__ sums, const float* __restrict__ gamma,
                           const float* __restrict__ beta, float* __restrict__ scale,
                           float* __restrict__ shift) {
  int c = blockIdx.x * 256 + threadIdx.x;
  float mu = sums[c] * (1.f / NROWS);
  float var = fmaxf(sums[HDEC + c] * (1.f / NROWS) - mu * mu, 0.f);
  float rstd = rsqrtf(var + 1e-3f);
  float sc = gamma[c] * rstd;
  scale[c] = sc;
  shift[c] = beta[c] - mu * sc;
}

__global__ void bn_apply_k(ushort_t* __restrict__ h1, const float* __restrict__ scale,
                           const float* __restrict__ shift) {
  size_t i8 = ((size_t)blockIdx.x * 256 + threadIdx.x) * 8;
  int col = (int)(i8 & (HDEC - 1));
  bh8 v = *(const bh8*)&h1[i8];
  bh8 o;
#pragma unroll
  for (int j = 0; j < 8; ++j) {
    float f = bf2f((ushort_t)v[j]);
    f = fmaxf(fmaf(f, scale[col + j], shift[col + j]), 0.f);
    o[j] = (short)f2bf(f);
  }
  *(bh8*)&h1[i8] = o;
}

// -------------------------------------------------------------------------------
extern "C" void kernel_launch(void* const* d_in, const int* in_sizes, int n_in,
                              void* d_out, int out_size, void* d_ws, size_t ws_size,
                              hipStream_t stream) {
  const float* x    = (const float*)d_in[0];
  const float* u1   = (const float*)d_in[1];
  const float* u2   = (const float*)d_in[2];
  const float* We1  = (const float*)d_in[3];
  const float* be1  = (const float*)d_in[4];
  const float* We2  = (const float*)d_in[5];
  const float* be2  = (const float*)d_in[6];
  const float* Wfc  = (const float*)d_in[7];
  const float* bfc  = (const float*)d_in[8];
  const float* Wg   = (const float*)d_in[9];
  const float* bg   = (const float*)d_in[10];
  const float* Wd1  = (const float*)d_in[11];
  const float* bd1  = (const float*)d_in[12];
  const float* gamma = (const float*)d_in[13];
  const float* beta  = (const float*)d_in[14];
  const float* Wd2  = (const float*)d_in[15];
  const float* bd2  = (const float*)d_in[16];
  (void)in_sizes; (void)n_in; (void)out_size;

  // outputs fp32: pred | assignment | feat
  float* out = (float*)d_out;
  float* pred_o   = out;
  float* assign_o = out + (size_t)NROWS * DIN;
  float* feat_o   = assign_o + (size_t)NROWS * KC;

  char* ws = (char*)d_ws;
  const size_t MB = 1024 * 1024;
  // R0 [0,32MB): ench (f32 fallback | hi/lo split) -> then gcn hi/lo + Wd1T + bn
  float*    ench    = (float*)(ws + 0);                       // fallback path only
  ushort_t* ench_hi = (ushort_t*)(ws + 0);                    // [0,16MB)
  ushort_t* ench_lo = (ushort_t*)(ws + 16 * MB);              // [16,32MB)
  ushort_t* gcn_hi  = (ushort_t*)(ws + 0);
  ushort_t* gcn_lo  = (ushort_t*)(ws + 8 * MB);
  ushort_t* Wd1T_hi = (ushort_t*)(ws + 16 * MB);              // written after enc2
  ushort_t* Wd1T_lo = (ushort_t*)(ws + 18 * MB);
  float*    tmat    = (float*)(ws + 20 * MB);
  float*    bnsum   = (float*)(ws + 21 * MB);                 // 2*2048 f32
  float*    bnscale = (float*)(ws + 21 * MB + 16 * 1024);
  float*    bnshift = (float*)(ws + 21 * MB + 24 * 1024);
  // R1 [32,65.5MB): x_hi (enc1 phase) -> feat hi/lo + fw (pre-decoder) -> h1 bf16
  ushort_t* feat_hi = (ushort_t*)(ws + 32 * MB);
  ushort_t* feat_lo = (ushort_t*)(ws + 40 * MB);
  float*    fw      = (float*)(ws + 48 * MB);
  ushort_t* h1      = (ushort_t*)(ws + 32 * MB);
  // R2 [66,90MB): WgT, logits, gmat, Wd2T, We2T — overlaps x_hi span; written
  // only AFTER enc1 has consumed x_hi/x_lo.
  ushort_t* WgT_hi  = (ushort_t*)(ws + 66 * MB);
  ushort_t* WgT_lo  = (ushort_t*)(ws + 66 * MB + 512 * 1024);
  float*    logits  = (float*)(ws + 67 * MB);
  float*    gmat    = (float*)(ws + 69 * MB);
  ushort_t* Wd2T    = (ushort_t*)(ws + 71 * MB);
  ushort_t* We2T_hi = (ushort_t*)(ws + 87 * MB);
  ushort_t* We2T_lo = (ushort_t*)(ws + 88 * MB);
  // enc1 split scratch (dead after enc1): x_hi [32,96), x_lo [96,160), We1T [160,176)
  ushort_t* x_hi    = (ushort_t*)(ws + 32 * MB);
  ushort_t* x_lo    = (ushort_t*)(ws + 96 * MB);
  ushort_t* We1T_hi = (ushort_t*)(ws + 160 * MB);
  ushort_t* We1T_lo = (ushort_t*)(ws + 168 * MB);
  const bool use_split = (ws_size >= 176 * MB);

  if (use_split) {
    // ---- enc1: ench = relu(x @ We1 + be1), split-bf16 4-pass, hi/lo output ----
    tcast_k<true><<<dim3(HENC / 32, DIN / 32), 256, 0, stream>>>(We1, We1T_hi, We1T_lo, DIN, HENC);
    fsplit_k<<<dim3((NROWS * DIN / 8) / 256), 256, 0, stream>>>(x, x_hi, x_lo);
    gemm_bf16x2_k<2, true><<<dim3(HENC / 128, NROWS / 128), 256, 0, stream>>>(
        x_hi, x_lo, We1T_hi, We1T_lo, be1, nullptr, ench_hi, ench_lo, nullptr,
        NROWS, HENC, DIN);

    // x_hi/x_lo now dead -> safe to fill R2 (overlaps x_hi span)
    tcast_k<true><<<dim3(DM / 32, DM / 32), 256, 0, stream>>>(Wg, WgT_hi, WgT_lo, DM, DM);
    tcast_k<false><<<dim3(DIN / 32, HDEC / 32), 256, 0, stream>>>(Wd2, Wd2T, nullptr, HDEC, DIN);
    tcast_k<true><<<dim3(DM / 32, HENC / 32), 256, 0, stream>>>(We2, We2T_hi, We2T_lo, HENC, DM);

    // ---- enc2: feat = ench @ We2 + be2, split-bf16 4-pass, f32 + hi/lo out ----
    gemm_bf16x2_k<3, true><<<dim3(DM / 128, NROWS / 128), 256, 0, stream>>>(
        ench_hi, ench_lo, We2T_hi, We2T_lo, be2, feat_o, feat_hi, feat_lo, nullptr,
        NROWS, DM, HENC);
  } else {
    // ---- fallback: full fp32 encoder ----
    gemm_f32_k<128, 128, 0><<<dim3(HENC / 128, NROWS / 128), 256, 0, stream>>>(
        x, We1, be1, ench, nullptr, nullptr, NROWS, HENC, DIN);
    tcast_k<true><<<dim3(DM / 32, DM / 32), 256, 0, stream>>>(Wg, WgT_hi, WgT_lo, DM, DM);
    tcast_k<false><<<dim3(DIN / 32, HDEC / 32), 256, 0, stream>>>(Wd2, Wd2T, nullptr, HDEC, DIN);
    gemm_f32_k<64, 128, 1><<<dim3(DM / 128, NROWS / 64), 256, 0, stream>>>(
        ench, We2, be2, feat_o, feat_hi, feat_lo, NROWS, DM, HENC);
  }

  // ench now dead -> R0 [16,32MB) reusable for Wd1T
  tcast_k<true><<<dim3(HDEC / 32, DM / 32), 256, 0, stream>>>(Wd1, Wd1T_hi, Wd1T_lo, DM, HDEC);

  // ---- enc3: logits = feat @ Wfc + bfc (fp32 — argmax-accuracy-critical) ----
  gemm_f32_k<64, 64, 2><<<dim3(KC / 64, NROWS / 64), 256, 0, stream>>>(
      feat_o, Wfc, bfc, logits, nullptr, nullptr, NROWS, KC, DM);

  gumbel_k<<<dim3(NROWS / 4), 256, 0, stream>>>(logits, u1, u2, gmat, assign_o);

  // fw = feat @ Wg (split-bf16 3-pass, fp32-quality)
  gemm_bf16x2_k<0, false><<<dim3(DM / 128, NROWS / 128), 256, 0, stream>>>(
      feat_hi, feat_lo, WgT_hi, WgT_lo, nullptr, fw, nullptr, nullptr, nullptr,
      NROWS, DM, DM);

  // gcn = relu(g (g^T fw) + bg) — adjacency factored out; all f32
  hipMemsetAsync(tmat, 0, (size_t)KC * DM * 4, stream);
  gtfw_k<<<dim3(DM / 64, NROWS / 512), 256, 0, stream>>>(gmat, fw, tmat);
  gcn_k<<<dim3(DM / 64, NROWS / 64), 256, 0, stream>>>(gmat, tmat, bg, gcn_hi, gcn_lo);

  // h1 = gcn @ Wd1 + bd1 (split-bf16 3-pass) + fused BN stats from f32 acc
  hipMemsetAsync(bnsum, 0, 2 * HDEC * 4, stream);
  gemm_bf16x2_k<1, false><<<dim3(HDEC / 128, NROWS / 128), 256, 0, stream>>>(
      gcn_hi, gcn_lo, Wd1T_hi, Wd1T_lo, bd1, nullptr, h1, nullptr, bnsum,
      NROWS, HDEC, DM);

  // batch norm finalize + in-place apply (h1 -> hbn)
  bn_final_k<<<dim3(HDEC / 256), 256, 0, stream>>>(bnsum, gamma, beta, bnscale, bnshift);
  bn_apply_k<<<dim3((NROWS * HDEC / 8) / 256), 256, 0, stream>>>(h1, bnscale, bnshift);

  // pred = relu(hbn @ Wd2 + bd2) -> f32 d_out (single-pass bf16)
  gemm_bf16_k<2><<<dim3(DIN / 128, NROWS / 128), 256, 0, stream>>>(
      h1, Wd2T, bd2, pred_o, NROWS, DIN, HDEC);
}

// Round 7
// 784.387 us; speedup vs baseline: 1.7924x; 1.0846x over previous
//
#include <hip/hip_runtime.h>
#include <stdint.h>

typedef unsigned short ushort_t;
typedef float f32x4 __attribute__((ext_vector_type(4)));
typedef short bh8 __attribute__((ext_vector_type(8)));

#define NROWS 8192
#define DIN   4096
#define HENC  1024
#define DM    512
#define KC    64
#define HDEC  2048
#define FIXCAP 128
#define GAP_THRESH 2e-4f

__device__ __forceinline__ float bf2f(ushort_t u) {
  union { unsigned int i; float f; } v; v.i = ((unsigned int)u) << 16; return v.f;
}
__device__ __forceinline__ ushort_t f2bf(float f) {
  unsigned int x = __float_as_uint(f);
  unsigned int r = x + 0x7FFFu + ((x >> 16) & 1u);
  return (ushort_t)(r >> 16);
}
__device__ __forceinline__ void split_bf(float x, ushort_t& hi, ushort_t& lo) {
  ushort_t h = f2bf(x);
  hi = h;
  lo = f2bf(x - bf2f(h));
}
// XCD-aware bijective block swizzle (requires nwg % 8 == 0)
__device__ __forceinline__ void xcd_swz(int& bx, int& by) {
  const int nx = gridDim.x, ny = gridDim.y;
  const int nwg = nx * ny;
  const int orig = by * nx + bx;
  const int swz = (orig & 7) * (nwg >> 3) + (orig >> 3);
  bx = swz % nx; by = swz / nx;
}

// ---------------- fp32 tiled GEMM (encoder tail + fallback path) ----------------
// EPI: 0 = relu -> f32;  1 = f32 + bf16 hi/lo split;  2 = f32 plain
template<int BM, int BN, int EPI>
__launch_bounds__(256, 2)
__global__ void gemm_f32_k(const float* __restrict__ A, const float* __restrict__ B,
                           const float* __restrict__ bias, float* __restrict__ Cf,
                           ushort_t* __restrict__ Ch, ushort_t* __restrict__ Cl,
                           int M, int N, int K) {
  constexpr int TM = BM / 16, TN = BN / 16;
  __shared__ float As[16][BM + 4];
  __shared__ float Bs[16][BN + 4];
  const int t = threadIdx.x;
  const int tx = t & 15, ty = t >> 4;
  const int m0 = blockIdx.y * BM, n0 = blockIdx.x * BN;
  float acc[TM][TN];
#pragma unroll
  for (int i = 0; i < TM; ++i)
#pragma unroll
    for (int j = 0; j < TN; ++j) acc[i][j] = 0.f;

  const int ar = t >> 2, ac = (t & 3) * 4;
  const int bk = t >> 4;

  for (int k0 = 0; k0 < K; k0 += 16) {
#pragma unroll
    for (int ii = 0; ii < BM / 64; ++ii) {
      int rr = ar + ii * 64;
      float4 v = *(const float4*)(A + (size_t)(m0 + rr) * K + k0 + ac);
      As[ac + 0][rr] = v.x; As[ac + 1][rr] = v.y;
      As[ac + 2][rr] = v.z; As[ac + 3][rr] = v.w;
    }
#pragma unroll
    for (int jj = 0; jj < BN / 64; ++jj) {
      int nn = (t & 15) * 4 * (BN / 64) + jj * 4;
      float4 v = *(const float4*)(B + (size_t)(k0 + bk) * N + n0 + nn);
      *(float4*)&Bs[bk][nn] = v;
    }
    __syncthreads();
#pragma unroll
    for (int kk = 0; kk < 16; ++kk) {
      float a[TM], b[TN];
#pragma unroll
      for (int i = 0; i < TM; i += 4) {
        float4 v = *(const float4*)&As[kk][ty * TM + i];
        a[i] = v.x; a[i + 1] = v.y; a[i + 2] = v.z; a[i + 3] = v.w;
      }
#pragma unroll
      for (int j = 0; j < TN; j += 4) {
        float4 v = *(const float4*)&Bs[kk][tx * TN + j];
        b[j] = v.x; b[j + 1] = v.y; b[j + 2] = v.z; b[j + 3] = v.w;
      }
#pragma unroll
      for (int i = 0; i < TM; ++i)
#pragma unroll
        for (int j = 0; j < TN; ++j) acc[i][j] = fmaf(a[i], b[j], acc[i][j]);
    }
    __syncthreads();
  }
#pragma unroll
  for (int i = 0; i < TM; ++i) {
    int row = m0 + ty * TM + i;
#pragma unroll
    for (int j = 0; j < TN; ++j) {
      int col = n0 + tx * TN + j;
      float v = acc[i][j] + bias[col];
      if (EPI == 0) v = fmaxf(v, 0.f);
      Cf[(size_t)row * N + col] = v;
      if (EPI == 1) {
        ushort_t h, l; split_bf(v, h, l);
        Ch[(size_t)row * N + col] = h;
        Cl[(size_t)row * N + col] = l;
      }
    }
  }
}

// ---------------- bf16 MFMA GEMM, single pass: C = A[M,K] @ BT[N,K]^T ----------
__device__ __forceinline__ void async_cp16(const ushort_t* g, ushort_t* l) {
  __builtin_amdgcn_global_load_lds((const __attribute__((address_space(1))) unsigned int*)g,
                                   (__attribute__((address_space(3))) unsigned int*)l,
                                   16, 0, 0);
}

template<int EPI>
__launch_bounds__(256, 2)
__global__ void gemm_bf16_k(const ushort_t* __restrict__ A, const ushort_t* __restrict__ BT,
                            const float* __restrict__ bias, float* __restrict__ Cf,
                            int M, int N, int K) {
  __shared__ ushort_t lA[128 * 32];
  __shared__ ushort_t lB[128 * 32];
  const int t = threadIdx.x;
  const int w = t >> 6, lane = t & 63;
  const int wm = w >> 1, wn = w & 1;
  int bx = blockIdx.x, by = blockIdx.y;
  xcd_swz(bx, by);
  const int m0 = by * 128, n0 = bx * 128;
  f32x4 acc[4][4] = {};
  const int lr = lane & 15, lk = (lane >> 4) * 8;
  const int sm = lane >> 2, sk = (lane & 3) * 8;

  for (int k0 = 0; k0 < K; k0 += 32) {
#pragma unroll
    for (int q = 0; q < 2; ++q) {
      const int ci = w * 2 + q;
      const int mr = ci * 16 + sm;
      async_cp16(A  + (size_t)(m0 + mr) * K + k0 + sk, lA + ci * 512);
      async_cp16(BT + (size_t)(n0 + mr) * K + k0 + sk, lB + ci * 512);
    }
    __syncthreads();
    bh8 av[4], bv[4];
#pragma unroll
    for (int mi = 0; mi < 4; ++mi)
      av[mi] = *(const bh8*)&lA[(wm * 64 + mi * 16 + lr) * 32 + lk];
#pragma unroll
    for (int ni = 0; ni < 4; ++ni)
      bv[ni] = *(const bh8*)&lB[(wn * 64 + ni * 16 + lr) * 32 + lk];
#pragma unroll
    for (int mi = 0; mi < 4; ++mi)
#pragma unroll
      for (int ni = 0; ni < 4; ++ni)
        acc[mi][ni] = __builtin_amdgcn_mfma_f32_16x16x32_bf16(av[mi], bv[ni], acc[mi][ni], 0, 0, 0);
    __syncthreads();
  }
  const int rb = (lane >> 4) * 4;
#pragma unroll
  for (int mi = 0; mi < 4; ++mi) {
#pragma unroll
    for (int ni = 0; ni < 4; ++ni) {
      int col = n0 + wn * 64 + ni * 16 + lr;
      float bval = bias[col];
#pragma unroll
      for (int r = 0; r < 4; ++r) {
        int row = m0 + wm * 64 + mi * 16 + rb + r;
        float v = acc[mi][ni][r] + bval;
        if (EPI == 2) v = fmaxf(v, 0.f);
        Cf[(size_t)row * N + col] = v;
      }
    }
  }
}

// ---------------- split-bf16 multi-pass MFMA GEMM: fp32-quality -----------------
// P4=false: AhBh + AhBl + AlBh (3-pass); P4=true: + AlBl (4-pass)
// EPI: 0 = f32 out, no bias (fw)
//      1 = bf16 out (Cb) + bias + BN column stats (h1)
//      2 = bias + relu -> split hi/lo out (ench)
//      3 = bias -> f32 out (Cf) + split hi/lo out (feat)
template<int EPI, bool P4>
__launch_bounds__(256, 2)
__global__ void gemm_bf16x2_k(const ushort_t* __restrict__ Ah, const ushort_t* __restrict__ Al,
                              const ushort_t* __restrict__ Bh, const ushort_t* __restrict__ Bl,
                              const float* __restrict__ bias, float* __restrict__ Cf,
                              ushort_t* __restrict__ Cb, ushort_t* __restrict__ Cl,
                              float* __restrict__ bnsum, int M, int N, int K) {
  __shared__ ushort_t lAh[4096], lAl[4096], lBh[4096], lBl[4096];
  __shared__ float csum[128], csum2[128];
  const int t = threadIdx.x;
  const int w = t >> 6, lane = t & 63;
  const int wm = w >> 1, wn = w & 1;
  int bx = blockIdx.x, by = blockIdx.y;
  xcd_swz(bx, by);
  const int m0 = by * 128, n0 = bx * 128;
  f32x4 acc[4][4] = {};
  const int lr = lane & 15, lk = (lane >> 4) * 8;
  const int sm = lane >> 2, sk = (lane & 3) * 8;

  for (int k0 = 0; k0 < K; k0 += 32) {
#pragma unroll
    for (int q = 0; q < 2; ++q) {
      const int ci = w * 2 + q;
      const int mr = ci * 16 + sm;
      async_cp16(Ah + (size_t)(m0 + mr) * K + k0 + sk, lAh + ci * 512);
      async_cp16(Al + (size_t)(m0 + mr) * K + k0 + sk, lAl + ci * 512);
      async_cp16(Bh + (size_t)(n0 + mr) * K + k0 + sk, lBh + ci * 512);
      async_cp16(Bl + (size_t)(n0 + mr) * K + k0 + sk, lBl + ci * 512);
    }
    __syncthreads();
    bh8 avh[4], avl[4], bvh[4], bvl[4];
#pragma unroll
    for (int mi = 0; mi < 4; ++mi) {
      avh[mi] = *(const bh8*)&lAh[(wm * 64 + mi * 16 + lr) * 32 + lk];
      avl[mi] = *(const bh8*)&lAl[(wm * 64 + mi * 16 + lr) * 32 + lk];
    }
#pragma unroll
    for (int ni = 0; ni < 4; ++ni) {
      bvh[ni] = *(const bh8*)&lBh[(wn * 64 + ni * 16 + lr) * 32 + lk];
      bvl[ni] = *(const bh8*)&lBl[(wn * 64 + ni * 16 + lr) * 32 + lk];
    }
#pragma unroll
    for (int mi = 0; mi < 4; ++mi)
#pragma unroll
      for (int ni = 0; ni < 4; ++ni) {
        acc[mi][ni] = __builtin_amdgcn_mfma_f32_16x16x32_bf16(avh[mi], bvh[ni], acc[mi][ni], 0, 0, 0);
        acc[mi][ni] = __builtin_amdgcn_mfma_f32_16x16x32_bf16(avh[mi], bvl[ni], acc[mi][ni], 0, 0, 0);
        acc[mi][ni] = __builtin_amdgcn_mfma_f32_16x16x32_bf16(avl[mi], bvh[ni], acc[mi][ni], 0, 0, 0);
        if (P4)
          acc[mi][ni] = __builtin_amdgcn_mfma_f32_16x16x32_bf16(avl[mi], bvl[ni], acc[mi][ni], 0, 0, 0);
      }
    __syncthreads();
  }
  if (EPI == 1) {
    if (t < 128) { csum[t] = 0.f; csum2[t] = 0.f; }
    __syncthreads();
  }
  const int rb = (lane >> 4) * 4;
#pragma unroll
  for (int mi = 0; mi < 4; ++mi) {
#pragma unroll
    for (int ni = 0; ni < 4; ++ni) {
      int lcol = wn * 64 + ni * 16 + lr;
      int col = n0 + lcol;
      float bval = (EPI == 0) ? 0.f : bias[col];
      float s = 0.f, s2 = 0.f;
#pragma unroll
      for (int r = 0; r < 4; ++r) {
        int row = m0 + wm * 64 + mi * 16 + rb + r;
        float v = acc[mi][ni][r] + bval;
        if (EPI == 0) {
          Cf[(size_t)row * N + col] = v;
        } else if (EPI == 1) {
          Cb[(size_t)row * N + col] = f2bf(v);
          s += v; s2 = fmaf(v, v, s2);
        } else if (EPI == 2) {
          v = fmaxf(v, 0.f);
          ushort_t h, l; split_bf(v, h, l);
          Cb[(size_t)row * N + col] = h;
          Cl[(size_t)row * N + col] = l;
        } else {  // EPI == 3
          Cf[(size_t)row * N + col] = v;
          ushort_t h, l; split_bf(v, h, l);
          Cb[(size_t)row * N + col] = h;
          Cl[(size_t)row * N + col] = l;
        }
      }
      if (EPI == 1) {
        atomicAdd(&csum[lcol], s);
        atomicAdd(&csum2[lcol], s2);
      }
    }
  }
  if (EPI == 1) {
    __syncthreads();
    if (t < 128) {
      atomicAdd(&bnsum[n0 + t], csum[t]);
      atomicAdd(&bnsum[N + n0 + t], csum2[t]);
    }
  }
}

// ---------------- transpose + cast: W f32 [K][N] -> WT bf16 [N][K] -------------
template<bool SPLIT>
__global__ void tcast_k(const float* __restrict__ W, ushort_t* __restrict__ WTh,
                        ushort_t* __restrict__ WTl, int K, int N) {
  __shared__ float tile[32][33];
  const int bx = blockIdx.x * 32, by = blockIdx.y * 32;
  const int tx = threadIdx.x & 31, ty8 = threadIdx.x >> 5;
  for (int i = ty8; i < 32; i += 8)
    tile[i][tx] = W[(size_t)(by + i) * N + bx + tx];
  __syncthreads();
  for (int i = ty8; i < 32; i += 8) {
    float v = tile[tx][i];
    if (SPLIT) {
      ushort_t h, l; split_bf(v, h, l);
      WTh[(size_t)(bx + i) * K + by + tx] = h;
      WTl[(size_t)(bx + i) * K + by + tx] = l;
    } else {
      WTh[(size_t)(bx + i) * K + by + tx] = f2bf(v);
    }
  }
}

// ---------------- elementwise f32 -> bf16 hi/lo split --------------------------
__global__ void fsplit_k(const float* __restrict__ X, ushort_t* __restrict__ H,
                         ushort_t* __restrict__ L) {
  size_t i8 = ((size_t)blockIdx.x * 256 + threadIdx.x) * 8;
  float4 a = *(const float4*)&X[i8];
  float4 b = *(const float4*)&X[i8 + 4];
  bh8 h, l;
  float vv[8] = {a.x, a.y, a.z, a.w, b.x, b.y, b.z, b.w};
#pragma unroll
  for (int j = 0; j < 8; ++j) {
    ushort_t hh, ll; split_bf(vv[j], hh, ll);
    h[j] = (short)hh; l[j] = (short)ll;
  }
  *(bh8*)&H[i8] = h;
  *(bh8*)&L[i8] = l;
}

// ---------------- gumbel softmax + hard assignment + near-tie flagging ---------
__global__ void gumbel_k(const float* __restrict__ logits, const float* __restrict__ u1,
                         const float* __restrict__ u2, float* __restrict__ gout,
                         float* __restrict__ assign, int* __restrict__ flags) {
  const int lane = threadIdx.x & 63;
  const int row = blockIdx.x * 4 + (threadIdx.x >> 6);
  const size_t off = (size_t)row * KC + lane;
  const float lg = logits[off];

  // soft sample from u1 -> l2-normalized g
  float gn = -logf(-logf(u1[off] + 1e-20f) + 1e-20f);
  float s = lg + gn;
  float m = s;
#pragma unroll
  for (int o = 32; o; o >>= 1) m = fmaxf(m, __shfl_xor(m, o, 64));
  float e = expf(s - m);
  float sum = e;
#pragma unroll
  for (int o = 32; o; o >>= 1) sum += __shfl_xor(sum, o, 64);
  float y = e / sum;
  float l2 = y * y;
#pragma unroll
  for (int o = 32; o; o >>= 1) l2 += __shfl_xor(l2, o, 64);
  gout[off] = y * rsqrtf(fmaxf(l2, 1e-12f));

  // hard sample from u2: top-2 (max, second, argmax-first) butterfly
  float gn2 = -logf(-logf(u2[off] + 1e-20f) + 1e-20f);
  float s2 = lg + gn2;
  float m2 = s2, sec = -__builtin_inff();
  int bi = lane;
#pragma unroll
  for (int o = 32; o; o >>= 1) {
    float om = __shfl_xor(m2, o, 64);
    float os = __shfl_xor(sec, o, 64);
    int   oi = __shfl_xor(bi, o, 64);
    if (om > m2 || (om == m2 && oi < bi)) {
      sec = fmaxf(m2, os); m2 = om; bi = oi;
    } else {
      sec = fmaxf(sec, om);
    }
  }
  assign[off] = (lane == bi) ? 1.0f : 0.0f;
  if (lane == 0 && (m2 - sec) < GAP_THRESH) {
    int idx = atomicAdd(&flags[0], 1);
    if (idx < FIXCAP) flags[1 + idx] = row;
  }
}

// ---------------- fp32 exact fixup for near-tie rows ---------------------------
// fixup1: partial ench (pre-bias/relu) for flagged rows; k-split over 64 blocks
__global__ void fixup1_k(const float* __restrict__ x, const float* __restrict__ We1,
                         const int* __restrict__ flags, float* __restrict__ ench_fix) {
  const int slot = blockIdx.y;
  if (slot >= flags[0] || slot >= FIXCAP) return;
  const int row = flags[1 + slot];
  const int k0 = blockIdx.x * 64;           // DIN/64 = 64 blocks
  const int t = threadIdx.x;                // 256 threads, 4 cols each
  float a0 = 0.f, a1 = 0.f, a2 = 0.f, a3 = 0.f;
  for (int k = 0; k < 64; ++k) {
    float xv = x[(size_t)row * DIN + k0 + k];
    float4 wv = *(const float4*)&We1[(size_t)(k0 + k) * HENC + t * 4];
    a0 = fmaf(xv, wv.x, a0); a1 = fmaf(xv, wv.y, a1);
    a2 = fmaf(xv, wv.z, a2); a3 = fmaf(xv, wv.w, a3);
  }
  float* dst = &ench_fix[(size_t)slot * HENC + t * 4];
  atomicAdd(dst + 0, a0); atomicAdd(dst + 1, a1);
  atomicAdd(dst + 2, a2); atomicAdd(dst + 3, a3);
}

// fixup2: partial feat (pre-bias) from relu(ench_fix + be1); k-split 16 blocks
__global__ void fixup2_k(const float* __restrict__ ench_fix, const float* __restrict__ be1,
                         const float* __restrict__ We2, const int* __restrict__ flags,
                         float* __restrict__ feat_fix) {
  const int slot = blockIdx.y;
  if (slot >= flags[0] || slot >= FIXCAP) return;
  const int k0 = blockIdx.x * 64;           // HENC/64 = 16 blocks
  const int t = threadIdx.x;                // 256 threads, 2 cols each
  float a0 = 0.f, a1 = 0.f;
  for (int k = 0; k < 64; ++k) {
    float ev = fmaxf(ench_fix[(size_t)slot * HENC + k0 + k] + be1[k0 + k], 0.f);
    float2 wv = *(const float2*)&We2[(size_t)(k0 + k) * DM + t * 2];
    a0 = fmaf(ev, wv.x, a0); a1 = fmaf(ev, wv.y, a1);
  }
  float* dst = &feat_fix[(size_t)slot * DM + t * 2];
  atomicAdd(dst + 0, a0); atomicAdd(dst + 1, a1);
}

// fixup3: logits + gumbel + argmax; rewrite one-hot row
__global__ void fixup3_k(const float* __restrict__ feat_fix, const float* __restrict__ be2,
                         const float* __restrict__ Wfc, const float* __restrict__ bfc,
                         const float* __restrict__ u2, const int* __restrict__ flags,
                         float* __restrict__ assign) {
  const int slot = blockIdx.x;
  if (slot >= flags[0] || slot >= FIXCAP) return;
  const int row = flags[1 + slot];
  const int t = threadIdx.x;                // 256 = 64 cols x 4 k-chunks
  const int c = t & 63, ks = t >> 6;
  __shared__ float red[4][64];
  __shared__ float sc[64];
  float a = 0.f;
  for (int k = ks * 128; k < ks * 128 + 128; ++k) {
    float fv = feat_fix[(size_t)slot * DM + k] + be2[k];
    a = fmaf(fv, Wfc[(size_t)k * KC + c], a);
  }
  red[ks][c] = a;
  __syncthreads();
  if (t < 64) {
    float lg = red[0][c] + red[1][c] + red[2][c] + red[3][c] + bfc[c];
    float uv = u2[(size_t)row * KC + c];
    float gn2 = -logf(-logf(uv + 1e-20f) + 1e-20f);
    sc[c] = lg + gn2;
  }
  __syncthreads();
  if (t == 0) {
    int bi = 0; float mv = sc[0];
    for (int k = 1; k < KC; ++k)
      if (sc[k] > mv) { mv = sc[k]; bi = k; }   // strict >: first-max like argmax
    for (int k = 0; k < KC; ++k)
      assign[(size_t)row * KC + k] = (k == bi) ? 1.0f : 0.0f;
  }
}

// ---------------- t = g^T @ fw ------------------------------------------------
__global__ void gtfw_k(const float* __restrict__ g, const float* __restrict__ fw,
                       float* __restrict__ tmat) {
  __shared__ float lf[64 * 64];
  __shared__ float lg[64 * 64];
  const int t = threadIdx.x;
  const int k = t & 63, ng = t >> 6;
  const int nb = blockIdx.x, rc = blockIdx.y;
  float acc[16];
#pragma unroll
  for (int j = 0; j < 16; ++j) acc[j] = 0.f;
  for (int rt = 0; rt < 8; ++rt) {
    const int r0 = rc * 512 + rt * 64;
#pragma unroll
    for (int j = 0; j < 4; ++j) {
      int e = t * 16 + j * 4;
      int rr = e >> 6, cc = e & 63;
      *(float4*)&lf[e] = *(const float4*)&fw[(size_t)(r0 + rr) * DM + nb * 64 + cc];
      *(float4*)&lg[e] = *(const float4*)&g[(size_t)(r0 + rr) * KC + cc];
    }
    __syncthreads();
    for (int r = 0; r < 64; ++r) {
      float gv = lg[r * 64 + k];
      const float* lrow = &lf[r * 64 + ng * 16];
#pragma unroll
      for (int j = 0; j < 16; j += 4) {
        float4 b = *(const float4*)&lrow[j];
        acc[j]     += gv * b.x; acc[j + 1] += gv * b.y;
        acc[j + 2] += gv * b.z; acc[j + 3] += gv * b.w;
      }
    }
    __syncthreads();
  }
#pragma unroll
  for (int j = 0; j < 16; ++j)
    atomicAdd(&tmat[(size_t)k * DM + nb * 64 + ng * 16 + j], acc[j]);
}

// ---------------- gcn = relu(g @ t + bg) -> bf16 hi/lo -------------------------
__global__ void gcn_k(const float* __restrict__ g, const float* __restrict__ tmat,
                      const float* __restrict__ bg, ushort_t* __restrict__ gh,
                      ushort_t* __restrict__ gl) {
  __shared__ float gs[64 * 68];
  __shared__ float ts[64 * 68];
  const int t = threadIdx.x;
  const int tx = t & 15, ty = t >> 4;
  const int m0 = blockIdx.y * 64, n0 = blockIdx.x * 64;
#pragma unroll
  for (int j = 0; j < 4; ++j) {
    int e = t * 16 + j * 4;
    int rr = e >> 6, cc = e & 63;
    *(float4*)&gs[rr * 68 + cc] = *(const float4*)&g[(size_t)(m0 + rr) * KC + cc];
    *(float4*)&ts[rr * 68 + cc] = *(const float4*)&tmat[(size_t)rr * DM + n0 + cc];
  }
  __syncthreads();
  float acc[4][4];
#pragma unroll
  for (int i = 0; i < 4; ++i)
#pragma unroll
    for (int j = 0; j < 4; ++j) acc[i][j] = 0.f;
  for (int kk = 0; kk < 64; ++kk) {
    float a[4];
#pragma unroll
    for (int i = 0; i < 4; ++i) a[i] = gs[(ty * 4 + i) * 68 + kk];
    float4 b = *(const float4*)&ts[kk * 68 + tx * 4];
#pragma unroll
    for (int i = 0; i < 4; ++i) {
      acc[i][0] = fmaf(a[i], b.x, acc[i][0]);
      acc[i][1] = fmaf(a[i], b.y, acc[i][1]);
      acc[i][2] = fmaf(a[i], b.z, acc[i][2]);
      acc[i][3] = fmaf(a[i], b.w, acc[i][3]);
    }
  }
#pragma unroll
  for (int i = 0; i < 4; ++i) {
    int row = m0 + ty * 4 + i;
#pragma unroll
    for (int j = 0; j < 4; ++j) {
      int col = n0 + tx * 4 + j;
      float v = fmaxf(acc[i][j] + bg[col], 0.f);
      ushort_t h, l; split_bf(v, h, l);
      gh[(size_t)row * DM + col] = h;
      gl[(size_t)row * DM + col] = l;
    }
  }
}

// ---------------- batch-norm finalize + in-place apply -------------------------
__global__ void bn_final_k(const float* __restrict__ sums, const float* __restrict__ gamma,
                           const float* __restrict__ beta, float* __restrict__ scale,
                           float* __restrict__ shift) {
  int c = blockIdx.x * 256 + threadIdx.x;
  float mu = sums[c] * (1.f / NROWS);
  float var = fmaxf(sums[HDEC + c] * (1.f / NROWS) - mu * mu, 0.f);
  float rstd = rsqrtf(var + 1e-3f);
  float sc = gamma[c] * rstd;
  scale[c] = sc;
  shift[c] = beta[c] - mu * sc;
}

__global__ void bn_apply_k(ushort_t* __restrict__ h1, const float* __restrict__ scale,
                           const float* __restrict__ shift) {
  size_t i8 = ((size_t)blockIdx.x * 256 + threadIdx.x) * 8;
  int col = (int)(i8 & (HDEC - 1));
  bh8 v = *(const bh8*)&h1[i8];
  bh8 o;
#pragma unroll
  for (int j = 0; j < 8; ++j) {
    float f = bf2f((ushort_t)v[j]);
    f = fmaxf(fmaf(f, scale[col + j], shift[col + j]), 0.f);
    o[j] = (short)f2bf(f);
  }
  *(bh8*)&h1[i8] = o;
}

// -------------------------------------------------------------------------------
extern "C" void kernel_launch(void* const* d_in, const int* in_sizes, int n_in,
                              void* d_out, int out_size, void* d_ws, size_t ws_size,
                              hipStream_t stream) {
  const float* x    = (const float*)d_in[0];
  const float* u1   = (const float*)d_in[1];
  const float* u2   = (const float*)d_in[2];
  const float* We1  = (const float*)d_in[3];
  const float* be1  = (const float*)d_in[4];
  const float* We2  = (const float*)d_in[5];
  const float* be2  = (const float*)d_in[6];
  const float* Wfc  = (const float*)d_in[7];
  const float* bfc  = (const float*)d_in[8];
  const float* Wg   = (const float*)d_in[9];
  const float* bg   = (const float*)d_in[10];
  const float* Wd1  = (const float*)d_in[11];
  const float* bd1  = (const float*)d_in[12];
  const float* gamma = (const float*)d_in[13];
  const float* beta  = (const float*)d_in[14];
  const float* Wd2  = (const float*)d_in[15];
  const float* bd2  = (const float*)d_in[16];
  (void)in_sizes; (void)n_in; (void)out_size;

  // outputs fp32: pred | assignment | feat
  float* out = (float*)d_out;
  float* pred_o   = out;
  float* assign_o = out + (size_t)NROWS * DIN;
  float* feat_o   = assign_o + (size_t)NROWS * KC;

  char* ws = (char*)d_ws;
  const size_t MB = 1024 * 1024;
  // R0 [0,32MB): ench (f32 fallback | hi/lo split) -> then gcn hi/lo + Wd1T + bn
  //              + fixup scratch at [22,32MB) (written only after enc2)
  float*    ench    = (float*)(ws + 0);                       // fallback path only
  ushort_t* ench_hi = (ushort_t*)(ws + 0);                    // [0,16MB)
  ushort_t* ench_lo = (ushort_t*)(ws + 16 * MB);              // [16,32MB)
  ushort_t* gcn_hi  = (ushort_t*)(ws + 0);
  ushort_t* gcn_lo  = (ushort_t*)(ws + 8 * MB);
  ushort_t* Wd1T_hi = (ushort_t*)(ws + 16 * MB);              // written after enc2
  ushort_t* Wd1T_lo = (ushort_t*)(ws + 18 * MB);
  float*    tmat    = (float*)(ws + 20 * MB);
  float*    bnsum   = (float*)(ws + 21 * MB);                 // 2*2048 f32
  float*    bnscale = (float*)(ws + 21 * MB + 16 * 1024);
  float*    bnshift = (float*)(ws + 21 * MB + 24 * 1024);
  int*      flags   = (int*)(ws + 22 * MB);                   // [0]=count, rows
  float*    ench_fix = (float*)(ws + 22 * MB + 4 * 1024);     // FIXCAP x 1024 f32
  float*    feat_fix = (float*)(ws + 22 * MB + 4 * 1024 + FIXCAP * HENC * 4);
  const size_t fix_bytes = 4 * 1024 + (size_t)FIXCAP * (HENC + DM) * 4;
  // R1 [32,65.5MB): x_hi (enc1 phase) -> feat hi/lo + fw (pre-decoder) -> h1 bf16
  ushort_t* feat_hi = (ushort_t*)(ws + 32 * MB);
  ushort_t* feat_lo = (ushort_t*)(ws + 40 * MB);
  float*    fw      = (float*)(ws + 48 * MB);
  ushort_t* h1      = (ushort_t*)(ws + 32 * MB);
  // R2 [66,90MB): WgT, logits, gmat, Wd2T, We2T — overlaps x_hi span; written
  // only AFTER enc1 has consumed x_hi/x_lo.
  ushort_t* WgT_hi  = (ushort_t*)(ws + 66 * MB);
  ushort_t* WgT_lo  = (ushort_t*)(ws + 66 * MB + 512 * 1024);
  float*    logits  = (float*)(ws + 67 * MB);
  float*    gmat    = (float*)(ws + 69 * MB);
  ushort_t* Wd2T    = (ushort_t*)(ws + 71 * MB);
  ushort_t* We2T_hi = (ushort_t*)(ws + 87 * MB);
  ushort_t* We2T_lo = (ushort_t*)(ws + 88 * MB);
  // enc1 split scratch (dead after enc1): x_hi [32,96), x_lo [96,160), We1T [160,176)
  ushort_t* x_hi    = (ushort_t*)(ws + 32 * MB);
  ushort_t* x_lo    = (ushort_t*)(ws + 96 * MB);
  ushort_t* We1T_hi = (ushort_t*)(ws + 160 * MB);
  ushort_t* We1T_lo = (ushort_t*)(ws + 168 * MB);
  const bool use_split = (ws_size >= 176 * MB);

  if (use_split) {
    // ---- enc1: ench = relu(x @ We1 + be1), split-bf16 3-pass, hi/lo output ----
    tcast_k<true><<<dim3(HENC / 32, DIN / 32), 256, 0, stream>>>(We1, We1T_hi, We1T_lo, DIN, HENC);
    fsplit_k<<<dim3((NROWS * DIN / 8) / 256), 256, 0, stream>>>(x, x_hi, x_lo);
    gemm_bf16x2_k<2, false><<<dim3(HENC / 128, NROWS / 128), 256, 0, stream>>>(
        x_hi, x_lo, We1T_hi, We1T_lo, be1, nullptr, ench_hi, ench_lo, nullptr,
        NROWS, HENC, DIN);

    // x_hi/x_lo now dead -> safe to fill R2 (overlaps x_hi span)
    tcast_k<true><<<dim3(DM / 32, DM / 32), 256, 0, stream>>>(Wg, WgT_hi, WgT_lo, DM, DM);
    tcast_k<false><<<dim3(DIN / 32, HDEC / 32), 256, 0, stream>>>(Wd2, Wd2T, nullptr, HDEC, DIN);
    tcast_k<true><<<dim3(DM / 32, HENC / 32), 256, 0, stream>>>(We2, We2T_hi, We2T_lo, HENC, DM);

    // ---- enc2: feat = ench @ We2 + be2, split-bf16 3-pass, f32 + hi/lo out ----
    gemm_bf16x2_k<3, false><<<dim3(DM / 128, NROWS / 128), 256, 0, stream>>>(
        ench_hi, ench_lo, We2T_hi, We2T_lo, be2, feat_o, feat_hi, feat_lo, nullptr,
        NROWS, DM, HENC);
  } else {
    // ---- fallback: full fp32 encoder ----
    gemm_f32_k<128, 128, 0><<<dim3(HENC / 128, NROWS / 128), 256, 0, stream>>>(
        x, We1, be1, ench, nullptr, nullptr, NROWS, HENC, DIN);
    tcast_k<true><<<dim3(DM / 32, DM / 32), 256, 0, stream>>>(Wg, WgT_hi, WgT_lo, DM, DM);
    tcast_k<false><<<dim3(DIN / 32, HDEC / 32), 256, 0, stream>>>(Wd2, Wd2T, nullptr, HDEC, DIN);
    gemm_f32_k<64, 128, 1><<<dim3(DM / 128, NROWS / 64), 256, 0, stream>>>(
        ench, We2, be2, feat_o, feat_hi, feat_lo, NROWS, DM, HENC);
  }

  // ench now dead -> R0 [16,32MB) reusable for Wd1T + fixup scratch
  tcast_k<true><<<dim3(HDEC / 32, DM / 32), 256, 0, stream>>>(Wd1, Wd1T_hi, Wd1T_lo, DM, HDEC);
  hipMemsetAsync(flags, 0, fix_bytes, stream);

  // ---- enc3: logits = feat @ Wfc + bfc (fp32 — argmax-accuracy-critical) ----
  gemm_f32_k<64, 64, 2><<<dim3(KC / 64, NROWS / 64), 256, 0, stream>>>(
      feat_o, Wfc, bfc, logits, nullptr, nullptr, NROWS, KC, DM);

  gumbel_k<<<dim3(NROWS / 4), 256, 0, stream>>>(logits, u1, u2, gmat, assign_o, flags);

  // near-tie rows: exact fp32 recompute of logits -> argmax -> rewrite one-hot
  fixup1_k<<<dim3(DIN / 64, FIXCAP), 256, 0, stream>>>(x, We1, flags, ench_fix);
  fixup2_k<<<dim3(HENC / 64, FIXCAP), 256, 0, stream>>>(ench_fix, be1, We2, flags, feat_fix);
  fixup3_k<<<dim3(FIXCAP), 256, 0, stream>>>(feat_fix, be2, Wfc, bfc, u2, flags, assign_o);

  // fw = feat @ Wg (split-bf16 3-pass, fp32-quality)
  gemm_bf16x2_k<0, false><<<dim3(DM / 128, NROWS / 128), 256, 0, stream>>>(
      feat_hi, feat_lo, WgT_hi, WgT_lo, nullptr, fw, nullptr, nullptr, nullptr,
      NROWS, DM, DM);

  // gcn = relu(g (g^T fw) + bg) — adjacency factored out; all f32
  hipMemsetAsync(tmat, 0, (size_t)KC * DM * 4, stream);
  gtfw_k<<<dim3(DM / 64, NROWS / 512), 256, 0, stream>>>(gmat, fw, tmat);
  gcn_k<<<dim3(DM / 64, NROWS / 64), 256, 0, stream>>>(gmat, tmat, bg, gcn_hi, gcn_lo);

  // h1 = gcn @ Wd1 + bd1 (split-bf16 3-pass) + fused BN stats from f32 acc
  hipMemsetAsync(bnsum, 0, 2 * HDEC * 4, stream);
  gemm_bf16x2_k<1, false><<<dim3(HDEC / 128, NROWS / 128), 256, 0, stream>>>(
      gcn_hi, gcn_lo, Wd1T_hi, Wd1T_lo, bd1, nullptr, h1, nullptr, bnsum,
      NROWS, HDEC, DM);

  // batch norm finalize + in-place apply (h1 -> hbn)
  bn_final_k<<<dim3(HDEC / 256), 256, 0, stream>>>(bnsum, gamma, beta, bnscale, bnshift);
  bn_apply_k<<<dim3((NROWS * HDEC / 8) / 256), 256, 0, stream>>>(h1, bnscale, bnshift);

  // pred = relu(hbn @ Wd2 + bd2) -> f32 d_out (single-pass bf16)
  gemm_bf16_k<2><<<dim3(DIN / 128, NROWS / 128), 256, 0, stream>>>(
      h1, Wd2T, bd2, pred_o, NROWS, DIN, HDEC);
}